// Round 2
// baseline (961.505 us; speedup 1.0000x reference)
//
#include <hip/hip_runtime.h>
#include <stdint.h>
#include <stddef.h>

// ---------------- problem constants ----------------
#define S_LEN 2048
#define HIDN  2048
#define HQ    16
#define HKV   4
#define HDIM  128
#define NQKV  3072      // HQ*D + 2*HKV*D
#define QBLK  32        // S/64
#define GHW   128
#define INTER 5632
#define NEGF  (-1e30f)
#define THRG  0.004f

typedef short bf16x8 __attribute__((ext_vector_type(8)));
typedef float f32x4  __attribute__((ext_vector_type(4)));

__device__ __forceinline__ short f2bf(float f) {
  union { float f; unsigned u; } v; v.f = f;
  unsigned r = (v.u + 0x7FFFu + ((v.u >> 16) & 1u)) >> 16;
  return (short)r;
}
__device__ __forceinline__ float bf2f(short s) {
  union { float f; unsigned u; } v; v.u = ((unsigned)(unsigned short)s) << 16;
  return v.f;
}
__device__ __forceinline__ void gload16(const void* g, void* l) {
  __builtin_amdgcn_global_load_lds(
      (const __attribute__((address_space(1))) void*)g,
      (__attribute__((address_space(3))) void*)l, 16, 0, 0);
}

// ---------------- transpose + cast fp32 (R x C) -> bf16 (C x R) ----------------
__global__ __launch_bounds__(256) void k_transpose_cast(
    const float* __restrict__ src, short* __restrict__ dst, int R, int C) {
  __shared__ float t[32][33];
  const int tx = threadIdx.x, ty = threadIdx.y;
  const int x = blockIdx.x * 32 + tx;
  const int y0 = blockIdx.y * 32;
#pragma unroll
  for (int i = 0; i < 4; i++) {
    int yy = ty + i * 8;
    t[yy][tx] = src[(long)(y0 + yy) * C + x];
  }
  __syncthreads();
  const int xo = blockIdx.y * 32 + tx;
  const int yo0 = blockIdx.x * 32;
#pragma unroll
  for (int i = 0; i < 4; i++) {
    int yy = ty + i * 8;
    dst[(long)(yo0 + yy) * R + xo] = f2bf(t[tx][yy]);
  }
}

// ---------------- concat qkv bias ----------------
__global__ void k_bias_concat(const float* __restrict__ bq, const float* __restrict__ bk,
                              const float* __restrict__ bv, float* __restrict__ out) {
  int i = blockIdx.x * 256 + threadIdx.x;
  if (i < 2048) out[i] = bq[i];
  else if (i < 2560) out[i] = bk[i - 2048];
  else out[i] = bv[i - 2560];
}

// ---------------- RMSNorm fp32 -> bf16 ----------------
__global__ __launch_bounds__(256) void k_rms(const float* __restrict__ x,
                                             const float* __restrict__ w,
                                             short* __restrict__ out) {
  const int row = blockIdx.x;
  const float* xr = x + (long)row * HIDN;
  float v[8];
  float ss = 0.f;
#pragma unroll
  for (int i = 0; i < 8; i++) {
    v[i] = xr[threadIdx.x + i * 256];
    ss += v[i] * v[i];
  }
#pragma unroll
  for (int off = 32; off > 0; off >>= 1) ss += __shfl_down(ss, off, 64);
  __shared__ float red[4];
  const int wave = threadIdx.x >> 6, lane = threadIdx.x & 63;
  if (lane == 0) red[wave] = ss;
  __syncthreads();
  float tot = red[0] + red[1] + red[2] + red[3];
  float rs = rsqrtf(tot / (float)HIDN + 1e-6f);
#pragma unroll
  for (int i = 0; i < 8; i++) {
    int c = threadIdx.x + i * 256;
    out[(long)row * HIDN + c] = f2bf(v[i] * rs * w[c]);
  }
}

// ---------------- GEMM: C[M,N] = A[M,K](bf16) * Bt[N,K](bf16)^T  ----------------
// MODE 0: Cf = acc + bias? + add?   (fp32 out)
// MODE 1: Cb = bf16(acc)
// MODE 2: Cb = bf16(silu(gaux) * acc)
template <int MODE>
__global__ __launch_bounds__(256) void k_gemm(
    const short* __restrict__ A, const short* __restrict__ Bt,
    float* __restrict__ Cf, short* __restrict__ Cb,
    const float* __restrict__ bias, const float* __restrict__ add,
    const short* __restrict__ gaux, int M, int N, int K) {
  __shared__ short As[128 * 32];
  __shared__ short Bs[128 * 32];
  const int tid = threadIdx.x;
  const int wave = tid >> 6, lane = tid & 63, quad = lane >> 4, l15 = lane & 15;
  const long m0 = (long)blockIdx.y * 128, n0 = (long)blockIdx.x * 128;
  const int wr = (wave >> 1) * 64, wc = (wave & 1) * 64;
  f32x4 acc[4][4] = {};
  const int r4 = tid >> 2, c8 = (tid & 3) * 8;
  const short* Ag0 = A + (m0 + r4) * K + c8;
  const short* Ag1 = A + (m0 + 64 + r4) * K + c8;
  const short* Bg0 = Bt + (n0 + r4) * K + c8;
  const short* Bg1 = Bt + (n0 + 64 + r4) * K + c8;
  short* AsW0 = &As[wave * 512];
  short* AsW1 = &As[2048 + wave * 512];
  short* BsW0 = &Bs[wave * 512];
  short* BsW1 = &Bs[2048 + wave * 512];
  for (int k0 = 0; k0 < K; k0 += 32) {
    __syncthreads();
    gload16(Ag0 + k0, AsW0);
    gload16(Ag1 + k0, AsW1);
    gload16(Bg0 + k0, BsW0);
    gload16(Bg1 + k0, BsW1);
    __syncthreads();
    bf16x8 af[4], bb[4];
#pragma unroll
    for (int mi = 0; mi < 4; mi++)
      af[mi] = *(const bf16x8*)&As[(wr + mi * 16 + l15) * 32 + quad * 8];
#pragma unroll
    for (int ni = 0; ni < 4; ni++)
      bb[ni] = *(const bf16x8*)&Bs[(wc + ni * 16 + l15) * 32 + quad * 8];
#pragma unroll
    for (int mi = 0; mi < 4; mi++)
#pragma unroll
      for (int ni = 0; ni < 4; ni++)
        acc[mi][ni] = __builtin_amdgcn_mfma_f32_16x16x32_bf16(af[mi], bb[ni], acc[mi][ni], 0, 0, 0);
  }
  const bool hb = (MODE == 0) && (bias != nullptr);
  const bool ha = (MODE == 0) && (add != nullptr);
#pragma unroll
  for (int mi = 0; mi < 4; mi++) {
#pragma unroll
    for (int ni = 0; ni < 4; ni++) {
      long mbase = m0 + wr + mi * 16 + quad * 4;
      long n = n0 + wc + ni * 16 + l15;
#pragma unroll
      for (int r = 0; r < 4; r++) {
        float v = acc[mi][ni][r];
        long idx = (mbase + r) * N + n;
        if (MODE == 0) {
          if (hb) v += bias[n];
          if (ha) v += add[idx];
          Cf[idx] = v;
        } else if (MODE == 1) {
          Cb[idx] = f2bf(v);
        } else {
          float g = bf2f(gaux[idx]);
          float sg = g / (1.f + __expf(-g));
          Cb[idx] = f2bf(sg * v);
        }
      }
    }
  }
}

// ---------------- block means of q and k (pre-RoPE) ----------------
__global__ __launch_bounds__(256) void k_blockmean(const float* __restrict__ qkv,
                                                   float* __restrict__ qm,
                                                   float* __restrict__ km) {
  int id = blockIdx.x * 256 + threadIdx.x;  // 32 * 2560
  int qb = id / 2560, c = id % 2560;        // cols 0..2559 = q(2048) + k(512)
  const float* base = qkv + (long)qb * 64 * NQKV + c;
  float acc = 0.f;
  for (int s = 0; s < 64; s++) acc += base[(long)s * NQKV];
  acc *= (1.f / 64.f);
  if (c < 2048) qm[(long)qb * 2048 + c] = acc;
  else km[(long)qb * 512 + (c - 2048)] = acc;
}

// ---------------- gate projections qg = qm@gWq, kg = km@gWk ----------------
__global__ __launch_bounds__(128) void k_gateproj(const float* __restrict__ qm,
                                                  const float* __restrict__ km,
                                                  const float* __restrict__ gWq,
                                                  const float* __restrict__ gWk,
                                                  float* __restrict__ qg,
                                                  float* __restrict__ kg) {
  __shared__ float xm[128];
  const int b = blockIdx.x;
  const float* src; const float* W; float* dst;
  if (b < 512) { src = qm + (long)b * 128; W = gWq; dst = qg + (long)b * 128; }
  else { int r = b - 512; src = km + (long)r * 128; W = gWk; dst = kg + (long)r * 128; }
  xm[threadIdx.x] = src[threadIdx.x];
  __syncthreads();
  float acc = 0.f;
  for (int d = 0; d < 128; d++) acc += xm[d] * W[d * GHW + threadIdx.x];
  dst[threadIdx.x] = acc;
}

// ---------------- gate softmax + keep mask ----------------
__global__ __launch_bounds__(64) void k_gatemask(const float* __restrict__ qg,
                                                 const float* __restrict__ kg,
                                                 unsigned char* __restrict__ mask) {
  const int qb = blockIdx.x, h = blockIdx.y;
  __shared__ float qv[128];
  const int t = threadIdx.x;
  qv[t] = qg[((long)qb * 16 + h) * 128 + t];
  qv[t + 64] = qg[((long)qb * 16 + h) * 128 + t + 64];
  __syncthreads();
  const int kb = t;
  float s = NEGF;
  if (kb < 32 && kb <= qb) {
    const float* kr = kg + ((long)kb * 4 + (h >> 2)) * 128;
    float acc = 0.f;
    for (int d = 0; d < 128; d++) acc += qv[d] * kr[d];
    s = acc * 0.08838834764831845f;  // GH^-0.5
  }
  float m = s;
#pragma unroll
  for (int off = 32; off > 0; off >>= 1) m = fmaxf(m, __shfl_xor(m, off, 64));
  float e = (kb < 32 && kb <= qb) ? __expf(s - m) : 0.f;
  float sum = e;
#pragma unroll
  for (int off = 32; off > 0; off >>= 1) sum += __shfl_xor(sum, off, 64);
  if (kb < 32) {
    float gate = e / sum;
    bool keep = (kb <= qb) && (gate >= THRG || kb == qb);
    mask[((long)h * 32 + qb) * 32 + kb] = keep ? 1 : 0;
  }
}

// ---------------- RoPE + cast q,k -> head-major bf16 ----------------
__global__ __launch_bounds__(256) void k_rope(const float* __restrict__ qkv,
                                              const float* __restrict__ cosb,
                                              const float* __restrict__ sinb,
                                              short* __restrict__ q_bf,
                                              short* __restrict__ k_bf) {
  long id = (long)blockIdx.x * 256 + threadIdx.x;  // S * 20 * 64
  int d = (int)(id & 63);
  long rest = id >> 6;
  int head = (int)(rest % 20);
  int s = (int)(rest / 20);
  const float c = cosb[(long)s * HDIM + d];
  const float sn = sinb[(long)s * HDIM + d];
  if (head < HQ) {
    const float* src = qkv + (long)s * NQKV + head * HDIM;
    float x1 = src[d], x2 = src[d + 64];
    short* dst = q_bf + ((long)head * S_LEN + s) * HDIM;
    dst[d] = f2bf(x1 * c - x2 * sn);
    dst[d + 64] = f2bf(x2 * c + x1 * sn);
  } else {
    int hk = head - HQ;
    const float* src = qkv + (long)s * NQKV + 2048 + hk * HDIM;
    float x1 = src[d], x2 = src[d + 64];
    short* dst = k_bf + ((long)hk * S_LEN + s) * HDIM;
    dst[d] = f2bf(x1 * c - x2 * sn);
    dst[d + 64] = f2bf(x2 * c + x1 * sn);
  }
}

// ---------------- v transpose-cast: v_t[hk][d][s] ----------------
__global__ __launch_bounds__(256) void k_vcast(const float* __restrict__ qkv,
                                               short* __restrict__ v_t) {
  long id = (long)blockIdx.x * 256 + threadIdx.x;  // HKV*HDIM*S
  int s = (int)(id & (S_LEN - 1));
  long rest = id >> 11;
  int d = (int)(rest & 127);
  int hk = (int)(rest >> 7);
  v_t[id] = f2bf(qkv[(long)s * NQKV + 2560 + hk * HDIM + d]);
}

// ---------------- flash attention with block mask ----------------
// Wave-independent: no __syncthreads in the kb loop. Q/K/V fragments are
// loaded directly global->VGPR in MFMA layout (L1/L2-served; K block per
// head = 16 KB, whole K/V per head fits L2). Only the P C-layout->A-layout
// transpose round-trips a per-wave 2 KB LDS buffer with XOR-8 chunk swizzle
// (conflict-free ds_read_b128 / ~2-way writes).
__global__ __launch_bounds__(256) void k_attn(const short* __restrict__ q_bf,
                                              const short* __restrict__ k_bf,
                                              const short* __restrict__ v_t,
                                              const unsigned char* __restrict__ mask,
                                              short* __restrict__ o_bf) {
  const int qb = blockIdx.x, h = blockIdx.y;
  const int tid = threadIdx.x, wave = tid >> 6, lane = tid & 63;
  const int quad = lane >> 4, l15 = lane & 15;
  __shared__ short Ps[4 * 16 * 64];
  short* Pw = &Ps[wave * 1024];
  const int hk = h >> 2;
  const unsigned char* mptr = mask + ((long)h * 32 + qb) * 32;
  // scale folded with log2(e): softmax computed in exp2 domain
  const float SCL = 0.08838834764831845f * 1.4426950408889634f;

  // Q A-fragments, held in registers for the whole kernel
  bf16x8 aq[4];
  {
    const short* qrp =
        q_bf + ((long)h * S_LEN + (long)qb * 64 + wave * 16 + l15) * HDIM + quad * 8;
#pragma unroll
    for (int kd = 0; kd < 4; kd++) aq[kd] = *(const bf16x8*)(qrp + kd * 32);
  }

  f32x4 accO[8] = {};
  float mrow[4], lrow[4];
#pragma unroll
  for (int r = 0; r < 4; r++) { mrow[r] = -3.0e38f; lrow[r] = 0.f; }

  const short* kh = k_bf + (long)hk * S_LEN * HDIM;
  const short* vh = v_t + (long)hk * HDIM * S_LEN;

  for (int kb = 0; kb <= qb; kb++) {
    if (!mptr[kb]) continue;
    // ---- QK^T : 16 q-rows x 64 k-cols, K B-frags direct from global ----
    f32x4 sc[4];
    const short* kbase = kh + (long)kb * 64 * HDIM;
#pragma unroll
    for (int nt = 0; nt < 4; nt++) {
      const short* krp = kbase + (nt * 16 + l15) * HDIM + quad * 8;
      f32x4 a = {};
#pragma unroll
      for (int kd = 0; kd < 4; kd++) {
        bf16x8 bk = *(const bf16x8*)(krp + kd * 32);
        a = __builtin_amdgcn_mfma_f32_16x16x32_bf16(aq[kd], bk, a, 0, 0, 0);
      }
      sc[nt] = a;
    }
    // ---- online softmax, rows quad*4+r ----
#pragma unroll
    for (int r = 0; r < 4; r++) {
      const int qrow = quad * 4 + r;
      float sv[4];
#pragma unroll
      for (int nt = 0; nt < 4; nt++) {
        float x = sc[nt][r] * SCL;
        if (kb == qb && (nt * 16 + l15) > (wave * 16 + qrow)) x = NEGF;
        sv[nt] = x;
      }
      float mb = fmaxf(fmaxf(sv[0], sv[1]), fmaxf(sv[2], sv[3]));
#pragma unroll
      for (int off = 8; off > 0; off >>= 1) mb = fmaxf(mb, __shfl_xor(mb, off, 64));
      float mnew = fmaxf(mrow[r], mb);
      float alpha = exp2f(mrow[r] - mnew);
      float psum = 0.f;
#pragma unroll
      for (int nt = 0; nt < 4; nt++) {
        float p = exp2f(sv[nt] - mnew);
        psum += p;
        const int col = nt * 16 + l15;
        const int ch = (col >> 3) ^ (qrow & 7);  // XOR swizzle
        Pw[qrow * 64 + ch * 8 + (col & 7)] = f2bf(p);
      }
#pragma unroll
      for (int off = 8; off > 0; off >>= 1) psum += __shfl_xor(psum, off, 64);
      lrow[r] = lrow[r] * alpha + psum;
      mrow[r] = mnew;
#pragma unroll
      for (int dt = 0; dt < 8; dt++) accO[dt][r] *= alpha;
    }
    // drain LDS writes before fragment reads (per-wave buffer, DS in-order)
    asm volatile("s_waitcnt lgkmcnt(0)" ::: "memory");
    // ---- PV : P(16x64) @ V(64x128), V B-frags direct from global ----
    bf16x8 ap[2];
#pragma unroll
    for (int ksb = 0; ksb < 2; ksb++) {
      const int ch = (ksb * 4 + quad) ^ (l15 & 7);
      ap[ksb] = *(const bf16x8*)&Pw[l15 * 64 + ch * 8];
    }
    const short* vbase = vh + (long)kb * 64;
#pragma unroll
    for (int dt = 0; dt < 8; dt++) {
      const short* vrp = vbase + (long)(dt * 16 + l15) * S_LEN + quad * 8;
#pragma unroll
      for (int ksb = 0; ksb < 2; ksb++) {
        bf16x8 bv = *(const bf16x8*)(vrp + ksb * 32);
        accO[dt] = __builtin_amdgcn_mfma_f32_16x16x32_bf16(ap[ksb], bv, accO[dt], 0, 0, 0);
      }
    }
  }
#pragma unroll
  for (int r = 0; r < 4; r++) {
    float inv = 1.f / lrow[r];
    long srow = (long)qb * 64 + wave * 16 + quad * 4 + r;
#pragma unroll
    for (int dt = 0; dt < 8; dt++)
      o_bf[srow * HIDN + h * HDIM + dt * 16 + l15] = f2bf(accO[dt][r] * inv);
  }
}

// ---------------- workspace layout ----------------
static constexpr size_t SZ_WQKVT = (size_t)NQKV * HIDN * 2;
static constexpr size_t SZ_WOT = (size_t)HIDN * HIDN * 2;
static constexpr size_t SZ_WBIG = (size_t)INTER * HIDN * 2;
static constexpr size_t OFF_WQKVT = 0;
static constexpr size_t OFF_WOT = OFF_WQKVT + SZ_WQKVT;
static constexpr size_t OFF_WGATET = OFF_WOT + SZ_WOT;
static constexpr size_t OFF_WUPT = OFF_WGATET + SZ_WBIG;
static constexpr size_t OFF_WDOWNT = OFF_WUPT + SZ_WBIG;
static constexpr size_t OFF_BIAS = OFF_WDOWNT + SZ_WBIG;
static constexpr size_t OFF_MASK = OFF_BIAS + 3072 * 4 + 4096;
static constexpr size_t OFF_QM = OFF_MASK + 16 * 32 * 32 + 4096;
static constexpr size_t OFF_KM = OFF_QM + (size_t)32 * 16 * 128 * 4;
static constexpr size_t OFF_QG = OFF_KM + (size_t)32 * 4 * 128 * 4;
static constexpr size_t OFF_KG = OFF_QG + (size_t)32 * 16 * 128 * 4;
static constexpr size_t OFF_H2 = OFF_KG + (size_t)32 * 4 * 128 * 4;
static constexpr size_t OFF_H3 = OFF_H2 + (size_t)S_LEN * HIDN * 4;
static constexpr size_t OFF_REGA = OFF_H3 + (size_t)S_LEN * HIDN * 2;
//   REGA phase1: h_bf | q_bf | k_bf | v_t | o_bf ; phase2: act_bf (o_bf dead)
static constexpr size_t RA_HBF = 0;
static constexpr size_t RA_QBF = RA_HBF + (size_t)S_LEN * HIDN * 2;
static constexpr size_t RA_KBF = RA_QBF + (size_t)HQ * S_LEN * HDIM * 2;
static constexpr size_t RA_VT = RA_KBF + (size_t)HKV * S_LEN * HDIM * 2;
static constexpr size_t RA_OBF = RA_VT + (size_t)HKV * HDIM * S_LEN * 2;
static constexpr size_t SZ_REGA = RA_OBF + (size_t)S_LEN * HIDN * 2;
static constexpr size_t OFF_REGB = OFF_REGA + SZ_REGA;
//   REGB phase1: qkv_f32 (S x 3072 f32) ; phase2: g_bf (S x INTER bf16)
static constexpr size_t SZ_REGB = (size_t)S_LEN * NQKV * 4;
static constexpr size_t TOTAL_WS = OFF_REGB + SZ_REGB;

extern "C" void kernel_launch(void* const* d_in, const int* in_sizes, int n_in,
                              void* d_out, int out_size, void* d_ws, size_t ws_size,
                              hipStream_t stream) {
  const float* hidden = (const float*)d_in[0];
  const float* cosb = (const float*)d_in[1];
  const float* sinb = (const float*)d_in[2];
  const float* ln1 = (const float*)d_in[3];
  const float* ln2 = (const float*)d_in[4];
  const float* Wq = (const float*)d_in[5];
  const float* bq = (const float*)d_in[6];
  const float* Wk = (const float*)d_in[7];
  const float* bk = (const float*)d_in[8];
  const float* Wv = (const float*)d_in[9];
  const float* bv = (const float*)d_in[10];
  const float* Wo = (const float*)d_in[11];
  const float* gWq = (const float*)d_in[12];
  const float* gWk = (const float*)d_in[13];
  const float* Wgate = (const float*)d_in[14];
  const float* Wup = (const float*)d_in[15];
  const float* Wdown = (const float*)d_in[16];

  if (ws_size < TOTAL_WS) return;  // workspace too small; fail visibly

  char* ws = (char*)d_ws;
  short* WqkvT = (short*)(ws + OFF_WQKVT);
  short* WoT = (short*)(ws + OFF_WOT);
  short* WgateT = (short*)(ws + OFF_WGATET);
  short* WupT = (short*)(ws + OFF_WUPT);
  short* WdownT = (short*)(ws + OFF_WDOWNT);
  float* biasqkv = (float*)(ws + OFF_BIAS);
  unsigned char* maskb = (unsigned char*)(ws + OFF_MASK);
  float* qm = (float*)(ws + OFF_QM);
  float* km = (float*)(ws + OFF_KM);
  float* qg = (float*)(ws + OFF_QG);
  float* kg = (float*)(ws + OFF_KG);
  float* h2 = (float*)(ws + OFF_H2);
  short* h3_bf = (short*)(ws + OFF_H3);
  short* h_bf = (short*)(ws + OFF_REGA + RA_HBF);
  short* q_bf = (short*)(ws + OFF_REGA + RA_QBF);
  short* k_bf = (short*)(ws + OFF_REGA + RA_KBF);
  short* v_t = (short*)(ws + OFF_REGA + RA_VT);
  short* o_bf = (short*)(ws + OFF_REGA + RA_OBF);
  short* act_bf = (short*)(ws + OFF_REGA);  // overlays h_bf..v_t (+part of o_bf), all dead by then
  float* qkv_f = (float*)(ws + OFF_REGB);
  short* g_bf = (short*)(ws + OFF_REGB);  // overlays qkv_f, dead by then
  float* outp = (float*)d_out;

  dim3 tb(32, 8);
  // weight transposes (fp32 -> bf16, N x K)
  k_transpose_cast<<<dim3(64, 64), tb, 0, stream>>>(Wq, WqkvT, HIDN, 2048);
  k_transpose_cast<<<dim3(16, 64), tb, 0, stream>>>(Wk, WqkvT + (size_t)2048 * HIDN, HIDN, 512);
  k_transpose_cast<<<dim3(16, 64), tb, 0, stream>>>(Wv, WqkvT + (size_t)2560 * HIDN, HIDN, 512);
  k_transpose_cast<<<dim3(64, 64), tb, 0, stream>>>(Wo, WoT, HIDN, HIDN);
  k_transpose_cast<<<dim3(176, 64), tb, 0, stream>>>(Wgate, WgateT, HIDN, INTER);
  k_transpose_cast<<<dim3(176, 64), tb, 0, stream>>>(Wup, WupT, HIDN, INTER);
  k_transpose_cast<<<dim3(64, 176), tb, 0, stream>>>(Wdown, WdownT, INTER, HIDN);
  k_bias_concat<<<12, 256, 0, stream>>>(bq, bk, bv, biasqkv);

  // h = RMS(hidden, ln1) -> bf16
  k_rms<<<S_LEN, 256, 0, stream>>>(hidden, ln1, h_bf);
  // qkv = h @ [Wq|Wk|Wv] + bias  (fp32)
  k_gemm<0><<<dim3(NQKV / 128, S_LEN / 128), 256, 0, stream>>>(
      h_bf, WqkvT, qkv_f, nullptr, biasqkv, nullptr, nullptr, S_LEN, NQKV, HIDN);
  // gate path (pre-RoPE q,k)
  k_blockmean<<<320, 256, 0, stream>>>(qkv_f, qm, km);
  k_gateproj<<<640, 128, 0, stream>>>(qm, km, gWq, gWk, qg, kg);
  k_gatemask<<<dim3(32, 16), 64, 0, stream>>>(qg, kg, maskb);
  // RoPE + layout change
  k_rope<<<10240, 256, 0, stream>>>(qkv_f, cosb, sinb, q_bf, k_bf);
  k_vcast<<<4096, 256, 0, stream>>>(qkv_f, v_t);
  // attention
  k_attn<<<dim3(32, 16), 256, 0, stream>>>(q_bf, k_bf, v_t, maskb, o_bf);
  // h2 = o @ Wo + hidden (fp32)
  k_gemm<0><<<dim3(16, 16), 256, 0, stream>>>(
      o_bf, WoT, h2, nullptr, nullptr, hidden, nullptr, S_LEN, HIDN, HIDN);
  // h3 = RMS(h2, ln2) -> bf16
  k_rms<<<S_LEN, 256, 0, stream>>>(h2, ln2, h3_bf);
  // g = h3 @ Wgate (bf16)
  k_gemm<1><<<dim3(INTER / 128, 16), 256, 0, stream>>>(
      h3_bf, WgateT, nullptr, g_bf, nullptr, nullptr, nullptr, S_LEN, INTER, HIDN);
  // act = silu(g) * (h3 @ Wup) (bf16)
  k_gemm<2><<<dim3(INTER / 128, 16), 256, 0, stream>>>(
      h3_bf, WupT, nullptr, act_bf, nullptr, nullptr, g_bf, S_LEN, INTER, HIDN);
  // out = act @ Wdown + h2 (fp32)
  k_gemm<0><<<dim3(16, 16), 256, 0, stream>>>(
      act_bf, WdownT, outp, nullptr, nullptr, h2, nullptr, S_LEN, HIDN, INTER);
  (void)in_sizes; (void)n_in; (void)out_size;
}

// Round 3
// 925.553 us; speedup vs baseline: 1.0388x; 1.0388x over previous
//
#include <hip/hip_runtime.h>
#include <stdint.h>
#include <stddef.h>

// ---------------- problem constants ----------------
#define S_LEN 2048
#define HIDN  2048
#define HQ    16
#define HKV   4
#define HDIM  128
#define NQKV  3072      // HQ*D + 2*HKV*D
#define QBLK  32        // S/64
#define GHW   128
#define INTER 5632
#define NEGF  (-1e30f)
#define THRG  0.004f

typedef short bf16x8 __attribute__((ext_vector_type(8)));
typedef float f32x4  __attribute__((ext_vector_type(4)));

__device__ __forceinline__ short f2bf(float f) {
  union { float f; unsigned u; } v; v.f = f;
  unsigned r = (v.u + 0x7FFFu + ((v.u >> 16) & 1u)) >> 16;
  return (short)r;
}
__device__ __forceinline__ float bf2f(short s) {
  union { float f; unsigned u; } v; v.u = ((unsigned)(unsigned short)s) << 16;
  return v.f;
}
__device__ __forceinline__ void gload16(const void* g, void* l) {
  __builtin_amdgcn_global_load_lds(
      (const __attribute__((address_space(1))) void*)g,
      (__attribute__((address_space(3))) void*)l, 16, 0, 0);
}
// pack two f32 -> [bf16(hi)<<16 | bf16(lo)] via byte-select (truncation)
__device__ __forceinline__ unsigned pack_bf2(float hi, float lo) {
  return __builtin_amdgcn_perm(__float_as_uint(hi), __float_as_uint(lo), 0x07060302u);
}

// ---------------- transpose + cast fp32 (R x C) -> bf16 (C x R) ----------------
__global__ __launch_bounds__(256) void k_transpose_cast(
    const float* __restrict__ src, short* __restrict__ dst, int R, int C) {
  __shared__ float t[32][33];
  const int tx = threadIdx.x, ty = threadIdx.y;
  const int x = blockIdx.x * 32 + tx;
  const int y0 = blockIdx.y * 32;
#pragma unroll
  for (int i = 0; i < 4; i++) {
    int yy = ty + i * 8;
    t[yy][tx] = src[(long)(y0 + yy) * C + x];
  }
  __syncthreads();
  const int xo = blockIdx.y * 32 + tx;
  const int yo0 = blockIdx.x * 32;
#pragma unroll
  for (int i = 0; i < 4; i++) {
    int yy = ty + i * 8;
    dst[(long)(yo0 + yy) * R + xo] = f2bf(t[tx][yy]);
  }
}

// ---------------- concat qkv bias ----------------
__global__ void k_bias_concat(const float* __restrict__ bq, const float* __restrict__ bk,
                              const float* __restrict__ bv, float* __restrict__ out) {
  int i = blockIdx.x * 256 + threadIdx.x;
  if (i < 2048) out[i] = bq[i];
  else if (i < 2560) out[i] = bk[i - 2048];
  else out[i] = bv[i - 2560];
}

// ---------------- RMSNorm fp32 -> bf16 ----------------
__global__ __launch_bounds__(256) void k_rms(const float* __restrict__ x,
                                             const float* __restrict__ w,
                                             short* __restrict__ out) {
  const int row = blockIdx.x;
  const float* xr = x + (long)row * HIDN;
  float v[8];
  float ss = 0.f;
#pragma unroll
  for (int i = 0; i < 8; i++) {
    v[i] = xr[threadIdx.x + i * 256];
    ss += v[i] * v[i];
  }
#pragma unroll
  for (int off = 32; off > 0; off >>= 1) ss += __shfl_down(ss, off, 64);
  __shared__ float red[4];
  const int wave = threadIdx.x >> 6, lane = threadIdx.x & 63;
  if (lane == 0) red[wave] = ss;
  __syncthreads();
  float tot = red[0] + red[1] + red[2] + red[3];
  float rs = rsqrtf(tot / (float)HIDN + 1e-6f);
#pragma unroll
  for (int i = 0; i < 8; i++) {
    int c = threadIdx.x + i * 256;
    out[(long)row * HIDN + c] = f2bf(v[i] * rs * w[c]);
  }
}

// ---------------- GEMM: C[M,N] = A[M,K](bf16) * Bt[N,K](bf16)^T  ----------------
// MODE 0: Cf = acc + bias? + add?   (fp32 out)
// MODE 1: Cb = bf16(acc)
// MODE 2: Cb = bf16(silu(gaux) * acc)
// BN in {64,128}: N-tile width. BN=64 doubles the grid for small-grid GEMMs.
template <int MODE, int BN>
__global__ __launch_bounds__(256) void k_gemm(
    const short* __restrict__ A, const short* __restrict__ Bt,
    float* __restrict__ Cf, short* __restrict__ Cb,
    const float* __restrict__ bias, const float* __restrict__ add,
    const short* __restrict__ gaux, int M, int N, int K) {
  constexpr int NT = BN / 32;  // n-tiles per wave
  __shared__ short As[128 * 32];
  __shared__ short Bs[BN * 32];
  const int tid = threadIdx.x;
  const int wave = tid >> 6, lane = tid & 63, quad = lane >> 4, l15 = lane & 15;
  const long m0 = (long)blockIdx.y * 128, n0 = (long)blockIdx.x * BN;
  const int wr = (wave >> 1) * 64, wc = (wave & 1) * (BN / 2);
  f32x4 acc[4][NT] = {};
  const int r4 = tid >> 2, c8 = (tid & 3) * 8;
  const short* Ag0 = A + (m0 + r4) * K + c8;
  const short* Ag1 = A + (m0 + 64 + r4) * K + c8;
  const short* Bg0 = Bt + (n0 + r4) * K + c8;   // rows 0..63 (covers BN=64 fully)
  const short* Bg1 = Bt + (n0 + 64 + r4) * K + c8;
  short* AsW0 = &As[wave * 512];
  short* AsW1 = &As[2048 + wave * 512];
  short* BsW0 = &Bs[wave * 512];
  short* BsW1 = &Bs[2048 + wave * 512];
  for (int k0 = 0; k0 < K; k0 += 32) {
    __syncthreads();
    gload16(Ag0 + k0, AsW0);
    gload16(Ag1 + k0, AsW1);
    gload16(Bg0 + k0, BsW0);
    if constexpr (BN == 128) gload16(Bg1 + k0, BsW1);
    __syncthreads();
    bf16x8 af[4], bb[NT];
#pragma unroll
    for (int mi = 0; mi < 4; mi++)
      af[mi] = *(const bf16x8*)&As[(wr + mi * 16 + l15) * 32 + quad * 8];
#pragma unroll
    for (int ni = 0; ni < NT; ni++)
      bb[ni] = *(const bf16x8*)&Bs[(wc + ni * 16 + l15) * 32 + quad * 8];
#pragma unroll
    for (int mi = 0; mi < 4; mi++)
#pragma unroll
      for (int ni = 0; ni < NT; ni++)
        acc[mi][ni] = __builtin_amdgcn_mfma_f32_16x16x32_bf16(af[mi], bb[ni], acc[mi][ni], 0, 0, 0);
  }
  const bool hb = (MODE == 0) && (bias != nullptr);
  const bool ha = (MODE == 0) && (add != nullptr);
#pragma unroll
  for (int mi = 0; mi < 4; mi++) {
#pragma unroll
    for (int ni = 0; ni < NT; ni++) {
      long mbase = m0 + wr + mi * 16 + quad * 4;
      long n = n0 + wc + ni * 16 + l15;
#pragma unroll
      for (int r = 0; r < 4; r++) {
        float v = acc[mi][ni][r];
        long idx = (mbase + r) * N + n;
        if (MODE == 0) {
          if (hb) v += bias[n];
          if (ha) v += add[idx];
          Cf[idx] = v;
        } else if (MODE == 1) {
          Cb[idx] = f2bf(v);
        } else {
          float g = bf2f(gaux[idx]);
          float sg = g / (1.f + __expf(-g));
          Cb[idx] = f2bf(sg * v);
        }
      }
    }
  }
}

// ---------------- block means of q and k (pre-RoPE) ----------------
__global__ __launch_bounds__(256) void k_blockmean(const float* __restrict__ qkv,
                                                   float* __restrict__ qm,
                                                   float* __restrict__ km) {
  int id = blockIdx.x * 256 + threadIdx.x;  // 32 * 2560
  int qb = id / 2560, c = id % 2560;        // cols 0..2559 = q(2048) + k(512)
  const float* base = qkv + (long)qb * 64 * NQKV + c;
  float acc = 0.f;
  for (int s = 0; s < 64; s++) acc += base[(long)s * NQKV];
  acc *= (1.f / 64.f);
  if (c < 2048) qm[(long)qb * 2048 + c] = acc;
  else km[(long)qb * 512 + (c - 2048)] = acc;
}

// ---------------- gate projections qg = qm@gWq, kg = km@gWk ----------------
__global__ __launch_bounds__(128) void k_gateproj(const float* __restrict__ qm,
                                                  const float* __restrict__ km,
                                                  const float* __restrict__ gWq,
                                                  const float* __restrict__ gWk,
                                                  float* __restrict__ qg,
                                                  float* __restrict__ kg) {
  __shared__ float xm[128];
  const int b = blockIdx.x;
  const float* src; const float* W; float* dst;
  if (b < 512) { src = qm + (long)b * 128; W = gWq; dst = qg + (long)b * 128; }
  else { int r = b - 512; src = km + (long)r * 128; W = gWk; dst = kg + (long)r * 128; }
  xm[threadIdx.x] = src[threadIdx.x];
  __syncthreads();
  float acc = 0.f;
  for (int d = 0; d < 128; d++) acc += xm[d] * W[d * GHW + threadIdx.x];
  dst[threadIdx.x] = acc;
}

// ---------------- gate softmax + keep mask ----------------
__global__ __launch_bounds__(64) void k_gatemask(const float* __restrict__ qg,
                                                 const float* __restrict__ kg,
                                                 unsigned char* __restrict__ mask) {
  const int qb = blockIdx.x, h = blockIdx.y;
  __shared__ float qv[128];
  const int t = threadIdx.x;
  qv[t] = qg[((long)qb * 16 + h) * 128 + t];
  qv[t + 64] = qg[((long)qb * 16 + h) * 128 + t + 64];
  __syncthreads();
  const int kb = t;
  float s = NEGF;
  if (kb < 32 && kb <= qb) {
    const float* kr = kg + ((long)kb * 4 + (h >> 2)) * 128;
    float acc = 0.f;
    for (int d = 0; d < 128; d++) acc += qv[d] * kr[d];
    s = acc * 0.08838834764831845f;  // GH^-0.5
  }
  float m = s;
#pragma unroll
  for (int off = 32; off > 0; off >>= 1) m = fmaxf(m, __shfl_xor(m, off, 64));
  float e = (kb < 32 && kb <= qb) ? __expf(s - m) : 0.f;
  float sum = e;
#pragma unroll
  for (int off = 32; off > 0; off >>= 1) sum += __shfl_xor(sum, off, 64);
  if (kb < 32) {
    float gate = e / sum;
    bool keep = (kb <= qb) && (gate >= THRG || kb == qb);
    mask[((long)h * 32 + qb) * 32 + kb] = keep ? 1 : 0;
  }
}

// ---------------- RoPE + cast q,k -> head-major bf16 ----------------
__global__ __launch_bounds__(256) void k_rope(const float* __restrict__ qkv,
                                              const float* __restrict__ cosb,
                                              const float* __restrict__ sinb,
                                              short* __restrict__ q_bf,
                                              short* __restrict__ k_bf) {
  long id = (long)blockIdx.x * 256 + threadIdx.x;  // S * 20 * 64
  int d = (int)(id & 63);
  long rest = id >> 6;
  int head = (int)(rest % 20);
  int s = (int)(rest / 20);
  const float c = cosb[(long)s * HDIM + d];
  const float sn = sinb[(long)s * HDIM + d];
  if (head < HQ) {
    const float* src = qkv + (long)s * NQKV + head * HDIM;
    float x1 = src[d], x2 = src[d + 64];
    short* dst = q_bf + ((long)head * S_LEN + s) * HDIM;
    dst[d] = f2bf(x1 * c - x2 * sn);
    dst[d + 64] = f2bf(x2 * c + x1 * sn);
  } else {
    int hk = head - HQ;
    const float* src = qkv + (long)s * NQKV + 2048 + hk * HDIM;
    float x1 = src[d], x2 = src[d + 64];
    short* dst = k_bf + ((long)hk * S_LEN + s) * HDIM;
    dst[d] = f2bf(x1 * c - x2 * sn);
    dst[d + 64] = f2bf(x2 * c + x1 * sn);
  }
}

// ---------------- v transpose-cast: v_t[hk][d][s] ----------------
__global__ __launch_bounds__(256) void k_vcast(const float* __restrict__ qkv,
                                               short* __restrict__ v_t) {
  long id = (long)blockIdx.x * 256 + threadIdx.x;  // HKV*HDIM*S
  int s = (int)(id & (S_LEN - 1));
  long rest = id >> 11;
  int d = (int)(rest & 127);
  int hk = (int)(rest >> 7);
  v_t[id] = f2bf(qkv[(long)s * NQKV + 2560 + hk * HDIM + d]);
}

// ---------------- flash attention, S^T scheme ----------------
// Per-wave independent (no barriers). Computes S^T via mfma(K-frag, Q-frag):
// D col=l15 = q-row, so each lane owns ONE q-row; softmax is per-lane register
// reductions + 2 cross-quad shuffles. k-tile = 128 (two 64-blocks per iter).
// P written as packed b64 (4 cols/lane) into per-wave LDS with XOR-row chunk
// swizzle; read back as conflict-free b128 A-frags for PV.
__global__ __launch_bounds__(256) void k_attn(const short* __restrict__ q_bf,
                                              const short* __restrict__ k_bf,
                                              const short* __restrict__ v_t,
                                              const unsigned char* __restrict__ mask,
                                              short* __restrict__ o_bf) {
  const int qb = blockIdx.x, h = blockIdx.y;
  const int tid = threadIdx.x, wave = tid >> 6, lane = tid & 63;
  const int quad = lane >> 4, l15 = lane & 15;
  __shared__ short Ps[4 * 16 * 128];  // per-wave 16 rows x 128 cols (4 KB)
  short* Pw = &Ps[wave * 16 * 128];
  const int hk = h >> 2;
  const unsigned char* mptr = mask + ((long)h * 32 + qb) * 32;
  const float SCL = 0.08838834764831845f * 1.4426950408889634f;  // D^-.5 * log2e
  const int qrow_g = qb * 64 + wave * 16 + l15;  // this lane's q-row

  // Q B-frags (rows = q-rows, indexed by l15), resident all kernel
  bf16x8 bq[4];
  {
    const short* qrp = q_bf + ((long)h * S_LEN + qrow_g) * HDIM + quad * 8;
#pragma unroll
    for (int kd = 0; kd < 4; kd++) bq[kd] = *(const bf16x8*)(qrp + kd * 32);
  }

  f32x4 accO[8] = {};
  float mrow = -3.0e38f, lrow = 0.f;  // per-lane: row qrow_g

  const short* kh = k_bf + (long)hk * S_LEN * HDIM;
  const short* vh = v_t + (long)hk * HDIM * S_LEN;
  const int nkt = (qb + 2) >> 1;

  for (int kt = 0; kt < nkt; kt++) {
    const int kb0 = 2 * kt, kb1 = 2 * kt + 1;
    const bool m0 = mptr[kb0] != 0;
    const bool m1 = (kb1 <= qb) && (mptr[kb1] != 0);
    if (!m0 && !m1) continue;
    const int kbase = kt * 128;
    // ---- S^T: 8 subtiles; lane ends with 32 scores for its q-row ----
    f32x4 sv[8];
#pragma unroll
    for (int nt = 0; nt < 8; nt++) {
      const short* krp = kh + (long)(kbase + nt * 16 + l15) * HDIM + quad * 8;
      bf16x8 ka0 = *(const bf16x8*)(krp);
      bf16x8 ka1 = *(const bf16x8*)(krp + 32);
      bf16x8 ka2 = *(const bf16x8*)(krp + 64);
      bf16x8 ka3 = *(const bf16x8*)(krp + 96);
      f32x4 t = {};
      t = __builtin_amdgcn_mfma_f32_16x16x32_bf16(ka0, bq[0], t, 0, 0, 0);
      t = __builtin_amdgcn_mfma_f32_16x16x32_bf16(ka1, bq[1], t, 0, 0, 0);
      t = __builtin_amdgcn_mfma_f32_16x16x32_bf16(ka2, bq[2], t, 0, 0, 0);
      t = __builtin_amdgcn_mfma_f32_16x16x32_bf16(ka3, bq[3], t, 0, 0, 0);
      sv[nt] = t;
    }
    // ---- scale + mask + row max (per-lane regs, 2 shuffles) ----
    const bool easy = m0 && m1 && (kbase + 127 <= qb * 64 + wave * 16);
    float lmx = -__builtin_inff();
    if (easy) {
#pragma unroll
      for (int nt = 0; nt < 8; nt++)
#pragma unroll
        for (int r = 0; r < 4; r++) {
          sv[nt][r] *= SCL;
          lmx = fmaxf(lmx, sv[nt][r]);
        }
    } else {
#pragma unroll
      for (int nt = 0; nt < 8; nt++) {
        const bool mb = (nt < 4) ? m0 : m1;
#pragma unroll
        for (int r = 0; r < 4; r++) {
          const int kcol = kbase + nt * 16 + quad * 4 + r;
          const bool keep = mb && (kcol <= qrow_g);
          sv[nt][r] = keep ? sv[nt][r] * SCL : -__builtin_inff();
          lmx = fmaxf(lmx, sv[nt][r]);
        }
      }
    }
    lmx = fmaxf(lmx, __shfl_xor(lmx, 16, 64));
    lmx = fmaxf(lmx, __shfl_xor(lmx, 32, 64));
    const float mnew = fmaxf(mrow, lmx);
    const float alpha = __builtin_amdgcn_exp2f(mrow - mnew);
    mrow = mnew;
    // ---- exp2 + sum + packed P write ----
    float psum = 0.f;
#pragma unroll
    for (int nt = 0; nt < 8; nt++) {
#pragma unroll
      for (int r = 0; r < 4; r++) {
        float p = __builtin_amdgcn_exp2f(sv[nt][r] - mnew);
        sv[nt][r] = p;
        psum += p;
      }
      const int cpr = (2 * nt + (quad >> 1)) ^ l15;  // XOR-row chunk swizzle
      uint2 u;
      u.x = pack_bf2(sv[nt][1], sv[nt][0]);
      u.y = pack_bf2(sv[nt][3], sv[nt][2]);
      *(uint2*)&Pw[l15 * 128 + cpr * 8 + (quad & 1) * 4] = u;
    }
    psum += __shfl_xor(psum, 16, 64);
    psum += __shfl_xor(psum, 32, 64);
    lrow = lrow * alpha + psum;
    // ---- rescale accO (alpha broadcast: lane row l15 -> D-row quad*4+r) ----
    float al[4];
#pragma unroll
    for (int r = 0; r < 4; r++) al[r] = __shfl(alpha, quad * 4 + r, 64);
#pragma unroll
    for (int dt = 0; dt < 8; dt++)
#pragma unroll
      for (int r = 0; r < 4; r++) accO[dt][r] *= al[r];
    // drain LDS writes before fragment reads (per-wave buffer)
    asm volatile("s_waitcnt lgkmcnt(0)" ::: "memory");
    // ---- PV: P(16x128) @ V^T(128d x 128k) ----
    bf16x8 pf[4];
#pragma unroll
    for (int ksb = 0; ksb < 4; ksb++) {
      const int cpr = (ksb * 4 + quad) ^ l15;
      pf[ksb] = *(const bf16x8*)&Pw[l15 * 128 + cpr * 8];
    }
#pragma unroll
    for (int dt = 0; dt < 8; dt++) {
      const short* vrp = vh + (long)(dt * 16 + l15) * S_LEN + kbase + quad * 8;
#pragma unroll
      for (int ksb = 0; ksb < 4; ksb++) {
        bf16x8 vf = *(const bf16x8*)(vrp + ksb * 32);
        accO[dt] = __builtin_amdgcn_mfma_f32_16x16x32_bf16(pf[ksb], vf, accO[dt], 0, 0, 0);
      }
    }
  }
  // ---- epilogue: normalize by l (broadcast like alpha) and store ----
  const float linv = 1.f / lrow;
  float li[4];
#pragma unroll
  for (int r = 0; r < 4; r++) li[r] = __shfl(linv, quad * 4 + r, 64);
#pragma unroll
  for (int r = 0; r < 4; r++) {
    const long srow = (long)qb * 64 + wave * 16 + quad * 4 + r;
#pragma unroll
    for (int dt = 0; dt < 8; dt++)
      o_bf[srow * HIDN + h * HDIM + dt * 16 + l15] = f2bf(accO[dt][r] * li[r]);
  }
}

// ---------------- workspace layout ----------------
static constexpr size_t SZ_WQKVT = (size_t)NQKV * HIDN * 2;
static constexpr size_t SZ_WOT = (size_t)HIDN * HIDN * 2;
static constexpr size_t SZ_WBIG = (size_t)INTER * HIDN * 2;
static constexpr size_t OFF_WQKVT = 0;
static constexpr size_t OFF_WOT = OFF_WQKVT + SZ_WQKVT;
static constexpr size_t OFF_WGATET = OFF_WOT + SZ_WOT;
static constexpr size_t OFF_WUPT = OFF_WGATET + SZ_WBIG;
static constexpr size_t OFF_WDOWNT = OFF_WUPT + SZ_WBIG;
static constexpr size_t OFF_BIAS = OFF_WDOWNT + SZ_WBIG;
static constexpr size_t OFF_MASK = OFF_BIAS + 3072 * 4 + 4096;
static constexpr size_t OFF_QM = OFF_MASK + 16 * 32 * 32 + 4096;
static constexpr size_t OFF_KM = OFF_QM + (size_t)32 * 16 * 128 * 4;
static constexpr size_t OFF_QG = OFF_KM + (size_t)32 * 4 * 128 * 4;
static constexpr size_t OFF_KG = OFF_QG + (size_t)32 * 16 * 128 * 4;
static constexpr size_t OFF_H2 = OFF_KG + (size_t)32 * 4 * 128 * 4;
static constexpr size_t OFF_H3 = OFF_H2 + (size_t)S_LEN * HIDN * 4;
static constexpr size_t OFF_REGA = OFF_H3 + (size_t)S_LEN * HIDN * 2;
//   REGA phase1: h_bf | q_bf | k_bf | v_t | o_bf ; phase2: act_bf (o_bf dead)
static constexpr size_t RA_HBF = 0;
static constexpr size_t RA_QBF = RA_HBF + (size_t)S_LEN * HIDN * 2;
static constexpr size_t RA_KBF = RA_QBF + (size_t)HQ * S_LEN * HDIM * 2;
static constexpr size_t RA_VT = RA_KBF + (size_t)HKV * S_LEN * HDIM * 2;
static constexpr size_t RA_OBF = RA_VT + (size_t)HKV * HDIM * S_LEN * 2;
static constexpr size_t SZ_REGA = RA_OBF + (size_t)S_LEN * HIDN * 2;
static constexpr size_t OFF_REGB = OFF_REGA + SZ_REGA;
//   REGB phase1: qkv_f32 (S x 3072 f32) ; phase2: g_bf (S x INTER bf16)
static constexpr size_t SZ_REGB = (size_t)S_LEN * NQKV * 4;
static constexpr size_t TOTAL_WS = OFF_REGB + SZ_REGB;

extern "C" void kernel_launch(void* const* d_in, const int* in_sizes, int n_in,
                              void* d_out, int out_size, void* d_ws, size_t ws_size,
                              hipStream_t stream) {
  const float* hidden = (const float*)d_in[0];
  const float* cosb = (const float*)d_in[1];
  const float* sinb = (const float*)d_in[2];
  const float* ln1 = (const float*)d_in[3];
  const float* ln2 = (const float*)d_in[4];
  const float* Wq = (const float*)d_in[5];
  const float* bq = (const float*)d_in[6];
  const float* Wk = (const float*)d_in[7];
  const float* bk = (const float*)d_in[8];
  const float* Wv = (const float*)d_in[9];
  const float* bv = (const float*)d_in[10];
  const float* Wo = (const float*)d_in[11];
  const float* gWq = (const float*)d_in[12];
  const float* gWk = (const float*)d_in[13];
  const float* Wgate = (const float*)d_in[14];
  const float* Wup = (const float*)d_in[15];
  const float* Wdown = (const float*)d_in[16];

  if (ws_size < TOTAL_WS) return;  // workspace too small; fail visibly

  char* ws = (char*)d_ws;
  short* WqkvT = (short*)(ws + OFF_WQKVT);
  short* WoT = (short*)(ws + OFF_WOT);
  short* WgateT = (short*)(ws + OFF_WGATET);
  short* WupT = (short*)(ws + OFF_WUPT);
  short* WdownT = (short*)(ws + OFF_WDOWNT);
  float* biasqkv = (float*)(ws + OFF_BIAS);
  unsigned char* maskb = (unsigned char*)(ws + OFF_MASK);
  float* qm = (float*)(ws + OFF_QM);
  float* km = (float*)(ws + OFF_KM);
  float* qg = (float*)(ws + OFF_QG);
  float* kg = (float*)(ws + OFF_KG);
  float* h2 = (float*)(ws + OFF_H2);
  short* h3_bf = (short*)(ws + OFF_H3);
  short* h_bf = (short*)(ws + OFF_REGA + RA_HBF);
  short* q_bf = (short*)(ws + OFF_REGA + RA_QBF);
  short* k_bf = (short*)(ws + OFF_REGA + RA_KBF);
  short* v_t = (short*)(ws + OFF_REGA + RA_VT);
  short* o_bf = (short*)(ws + OFF_REGA + RA_OBF);
  short* act_bf = (short*)(ws + OFF_REGA);  // overlays h_bf..v_t, all dead by then
  float* qkv_f = (float*)(ws + OFF_REGB);
  short* g_bf = (short*)(ws + OFF_REGB);  // overlays qkv_f, dead by then
  float* outp = (float*)d_out;

  dim3 tb(32, 8);
  // weight transposes (fp32 -> bf16, N x K)
  k_transpose_cast<<<dim3(64, 64), tb, 0, stream>>>(Wq, WqkvT, HIDN, 2048);
  k_transpose_cast<<<dim3(16, 64), tb, 0, stream>>>(Wk, WqkvT + (size_t)2048 * HIDN, HIDN, 512);
  k_transpose_cast<<<dim3(16, 64), tb, 0, stream>>>(Wv, WqkvT + (size_t)2560 * HIDN, HIDN, 512);
  k_transpose_cast<<<dim3(64, 64), tb, 0, stream>>>(Wo, WoT, HIDN, HIDN);
  k_transpose_cast<<<dim3(176, 64), tb, 0, stream>>>(Wgate, WgateT, HIDN, INTER);
  k_transpose_cast<<<dim3(176, 64), tb, 0, stream>>>(Wup, WupT, HIDN, INTER);
  k_transpose_cast<<<dim3(64, 176), tb, 0, stream>>>(Wdown, WdownT, INTER, HIDN);
  k_bias_concat<<<12, 256, 0, stream>>>(bq, bk, bv, biasqkv);

  // h = RMS(hidden, ln1) -> bf16
  k_rms<<<S_LEN, 256, 0, stream>>>(hidden, ln1, h_bf);
  // qkv = h @ [Wq|Wk|Wv] + bias  (fp32)
  k_gemm<0, 64><<<dim3(NQKV / 64, S_LEN / 128), 256, 0, stream>>>(
      h_bf, WqkvT, qkv_f, nullptr, biasqkv, nullptr, nullptr, S_LEN, NQKV, HIDN);
  // gate path (pre-RoPE q,k)
  k_blockmean<<<320, 256, 0, stream>>>(qkv_f, qm, km);
  k_gateproj<<<640, 128, 0, stream>>>(qm, km, gWq, gWk, qg, kg);
  k_gatemask<<<dim3(32, 16), 64, 0, stream>>>(qg, kg, maskb);
  // RoPE + layout change
  k_rope<<<10240, 256, 0, stream>>>(qkv_f, cosb, sinb, q_bf, k_bf);
  k_vcast<<<4096, 256, 0, stream>>>(qkv_f, v_t);
  // attention
  k_attn<<<dim3(32, 16), 256, 0, stream>>>(q_bf, k_bf, v_t, maskb, o_bf);
  // h2 = o @ Wo + hidden (fp32)
  k_gemm<0, 64><<<dim3(32, 16), 256, 0, stream>>>(
      o_bf, WoT, h2, nullptr, nullptr, hidden, nullptr, S_LEN, HIDN, HIDN);
  // h3 = RMS(h2, ln2) -> bf16
  k_rms<<<S_LEN, 256, 0, stream>>>(h2, ln2, h3_bf);
  // g = h3 @ Wgate (bf16)
  k_gemm<1, 128><<<dim3(INTER / 128, 16), 256, 0, stream>>>(
      h3_bf, WgateT, nullptr, g_bf, nullptr, nullptr, nullptr, S_LEN, INTER, HIDN);
  // act = silu(g) * (h3 @ Wup) (bf16)
  k_gemm<2, 128><<<dim3(INTER / 128, 16), 256, 0, stream>>>(
      h3_bf, WupT, nullptr, act_bf, nullptr, nullptr, g_bf, S_LEN, INTER, HIDN);
  // out = act @ Wdown + h2 (fp32)
  k_gemm<0, 64><<<dim3(32, 16), 256, 0, stream>>>(
      act_bf, WdownT, outp, nullptr, nullptr, h2, nullptr, S_LEN, HIDN, INTER);
  (void)in_sizes; (void)n_in; (void)out_size;
}

// Round 4
// 746.694 us; speedup vs baseline: 1.2877x; 1.2395x over previous
//
#include <hip/hip_runtime.h>
#include <stdint.h>
#include <stddef.h>

// ---------------- problem constants ----------------
#define S_LEN 2048
#define HIDN  2048
#define HQ    16
#define HKV   4
#define HDIM  128
#define NQKV  3072      // HQ*D + 2*HKV*D
#define QBLK  32        // S/64
#define GHW   128
#define INTER 5632
#define NEGF  (-1e30f)
#define THRG  0.004f

typedef short bf16x8 __attribute__((ext_vector_type(8)));
typedef float f32x4  __attribute__((ext_vector_type(4)));

__device__ __forceinline__ short f2bf(float f) {
  union { float f; unsigned u; } v; v.f = f;
  unsigned r = (v.u + 0x7FFFu + ((v.u >> 16) & 1u)) >> 16;
  return (short)r;
}
__device__ __forceinline__ float bf2f(short s) {
  union { float f; unsigned u; } v; v.u = ((unsigned)(unsigned short)s) << 16;
  return v.f;
}
__device__ __forceinline__ void gload16(const void* g, void* l) {
  __builtin_amdgcn_global_load_lds(
      (const __attribute__((address_space(1))) void*)g,
      (__attribute__((address_space(3))) void*)l, 16, 0, 0);
}
// pack two f32 -> [bf16(hi)<<16 | bf16(lo)] via byte-select (truncation)
__device__ __forceinline__ unsigned pack_bf2(float hi, float lo) {
  return __builtin_amdgcn_perm(__float_as_uint(hi), __float_as_uint(lo), 0x07060302u);
}

// ---------------- transpose + cast fp32 (R x C) -> bf16 (C x R) ----------------
__global__ __launch_bounds__(256) void k_transpose_cast(
    const float* __restrict__ src, short* __restrict__ dst, int R, int C) {
  __shared__ float t[32][33];
  const int tx = threadIdx.x, ty = threadIdx.y;
  const int x = blockIdx.x * 32 + tx;
  const int y0 = blockIdx.y * 32;
#pragma unroll
  for (int i = 0; i < 4; i++) {
    int yy = ty + i * 8;
    t[yy][tx] = src[(long)(y0 + yy) * C + x];
  }
  __syncthreads();
  const int xo = blockIdx.y * 32 + tx;
  const int yo0 = blockIdx.x * 32;
#pragma unroll
  for (int i = 0; i < 4; i++) {
    int yy = ty + i * 8;
    dst[(long)(yo0 + yy) * R + xo] = f2bf(t[tx][yy]);
  }
}

// ---------------- concat qkv bias ----------------
__global__ void k_bias_concat(const float* __restrict__ bq, const float* __restrict__ bk,
                              const float* __restrict__ bv, float* __restrict__ out) {
  int i = blockIdx.x * 256 + threadIdx.x;
  if (i < 2048) out[i] = bq[i];
  else if (i < 2560) out[i] = bk[i - 2048];
  else out[i] = bv[i - 2560];
}

// ---------------- RMSNorm fp32 -> bf16 ----------------
__global__ __launch_bounds__(256) void k_rms(const float* __restrict__ x,
                                             const float* __restrict__ w,
                                             short* __restrict__ out) {
  const int row = blockIdx.x;
  const float* xr = x + (long)row * HIDN;
  float v[8];
  float ss = 0.f;
#pragma unroll
  for (int i = 0; i < 8; i++) {
    v[i] = xr[threadIdx.x + i * 256];
    ss += v[i] * v[i];
  }
#pragma unroll
  for (int off = 32; off > 0; off >>= 1) ss += __shfl_down(ss, off, 64);
  __shared__ float red[4];
  const int wave = threadIdx.x >> 6, lane = threadIdx.x & 63;
  if (lane == 0) red[wave] = ss;
  __syncthreads();
  float tot = red[0] + red[1] + red[2] + red[3];
  float rs = rsqrtf(tot / (float)HIDN + 1e-6f);
#pragma unroll
  for (int i = 0; i < 8; i++) {
    int c = threadIdx.x + i * 256;
    out[(long)row * HIDN + c] = f2bf(v[i] * rs * w[c]);
  }
}

// ---------------- GEMM: C[M,N] = A[M,K](bf16) * Bt[N,K](bf16)^T  ----------------
// MODE 0: Cf = acc + bias? + add?   (fp32 out)
// MODE 1: Cb = bf16(acc)
// MODE 2: Cb = bf16(silu(gaux) * acc)
// BN in {64,128}: N-tile width. BN=64 doubles the grid for small-grid GEMMs.
template <int MODE, int BN>
__global__ __launch_bounds__(256) void k_gemm(
    const short* __restrict__ A, const short* __restrict__ Bt,
    float* __restrict__ Cf, short* __restrict__ Cb,
    const float* __restrict__ bias, const float* __restrict__ add,
    const short* __restrict__ gaux, int M, int N, int K) {
  constexpr int NT = BN / 32;  // n-tiles per wave
  __shared__ short As[128 * 32];
  __shared__ short Bs[BN * 32];
  const int tid = threadIdx.x;
  const int wave = tid >> 6, lane = tid & 63, quad = lane >> 4, l15 = lane & 15;
  const long m0 = (long)blockIdx.y * 128, n0 = (long)blockIdx.x * BN;
  const int wr = (wave >> 1) * 64, wc = (wave & 1) * (BN / 2);
  f32x4 acc[4][NT] = {};
  const int r4 = tid >> 2, c8 = (tid & 3) * 8;
  const short* Ag0 = A + (m0 + r4) * K + c8;
  const short* Ag1 = A + (m0 + 64 + r4) * K + c8;
  const short* Bg0 = Bt + (n0 + r4) * K + c8;   // rows 0..63 (covers BN=64 fully)
  const short* Bg1 = Bt + (n0 + 64 + r4) * K + c8;
  short* AsW0 = &As[wave * 512];
  short* AsW1 = &As[2048 + wave * 512];
  short* BsW0 = &Bs[wave * 512];
  short* BsW1 = &Bs[2048 + wave * 512];
  for (int k0 = 0; k0 < K; k0 += 32) {
    __syncthreads();
    gload16(Ag0 + k0, AsW0);
    gload16(Ag1 + k0, AsW1);
    gload16(Bg0 + k0, BsW0);
    if constexpr (BN == 128) gload16(Bg1 + k0, BsW1);
    __syncthreads();
    bf16x8 af[4], bb[NT];
#pragma unroll
    for (int mi = 0; mi < 4; mi++)
      af[mi] = *(const bf16x8*)&As[(wr + mi * 16 + l15) * 32 + quad * 8];
#pragma unroll
    for (int ni = 0; ni < NT; ni++)
      bb[ni] = *(const bf16x8*)&Bs[(wc + ni * 16 + l15) * 32 + quad * 8];
#pragma unroll
    for (int mi = 0; mi < 4; mi++)
#pragma unroll
      for (int ni = 0; ni < NT; ni++)
        acc[mi][ni] = __builtin_amdgcn_mfma_f32_16x16x32_bf16(af[mi], bb[ni], acc[mi][ni], 0, 0, 0);
  }
  const bool hb = (MODE == 0) && (bias != nullptr);
  const bool ha = (MODE == 0) && (add != nullptr);
#pragma unroll
  for (int mi = 0; mi < 4; mi++) {
#pragma unroll
    for (int ni = 0; ni < NT; ni++) {
      long mbase = m0 + wr + mi * 16 + quad * 4;
      long n = n0 + wc + ni * 16 + l15;
#pragma unroll
      for (int r = 0; r < 4; r++) {
        float v = acc[mi][ni][r];
        long idx = (mbase + r) * N + n;
        if (MODE == 0) {
          if (hb) v += bias[n];
          if (ha) v += add[idx];
          Cf[idx] = v;
        } else if (MODE == 1) {
          Cb[idx] = f2bf(v);
        } else {
          float g = bf2f(gaux[idx]);
          float sg = g / (1.f + __expf(-g));
          Cb[idx] = f2bf(sg * v);
        }
      }
    }
  }
}

// ---------------- block means of q and k (pre-RoPE) ----------------
__global__ __launch_bounds__(256) void k_blockmean(const float* __restrict__ qkv,
                                                   float* __restrict__ qm,
                                                   float* __restrict__ km) {
  int id = blockIdx.x * 256 + threadIdx.x;  // 32 * 2560
  int qb = id / 2560, c = id % 2560;        // cols 0..2559 = q(2048) + k(512)
  const float* base = qkv + (long)qb * 64 * NQKV + c;
  float acc = 0.f;
  for (int s = 0; s < 64; s++) acc += base[(long)s * NQKV];
  acc *= (1.f / 64.f);
  if (c < 2048) qm[(long)qb * 2048 + c] = acc;
  else km[(long)qb * 512 + (c - 2048)] = acc;
}

// ---------------- gate projections qg = qm@gWq, kg = km@gWk ----------------
__global__ __launch_bounds__(128) void k_gateproj(const float* __restrict__ qm,
                                                  const float* __restrict__ km,
                                                  const float* __restrict__ gWq,
                                                  const float* __restrict__ gWk,
                                                  float* __restrict__ qg,
                                                  float* __restrict__ kg) {
  __shared__ float xm[128];
  const int b = blockIdx.x;
  const float* src; const float* W; float* dst;
  if (b < 512) { src = qm + (long)b * 128; W = gWq; dst = qg + (long)b * 128; }
  else { int r = b - 512; src = km + (long)r * 128; W = gWk; dst = kg + (long)r * 128; }
  xm[threadIdx.x] = src[threadIdx.x];
  __syncthreads();
  float acc = 0.f;
  for (int d = 0; d < 128; d++) acc += xm[d] * W[d * GHW + threadIdx.x];
  dst[threadIdx.x] = acc;
}

// ---------------- gate softmax + keep mask ----------------
__global__ __launch_bounds__(64) void k_gatemask(const float* __restrict__ qg,
                                                 const float* __restrict__ kg,
                                                 unsigned char* __restrict__ mask) {
  const int qb = blockIdx.x, h = blockIdx.y;
  __shared__ float qv[128];
  const int t = threadIdx.x;
  qv[t] = qg[((long)qb * 16 + h) * 128 + t];
  qv[t + 64] = qg[((long)qb * 16 + h) * 128 + t + 64];
  __syncthreads();
  const int kb = t;
  float s = NEGF;
  if (kb < 32 && kb <= qb) {
    const float* kr = kg + ((long)kb * 4 + (h >> 2)) * 128;
    float acc = 0.f;
    for (int d = 0; d < 128; d++) acc += qv[d] * kr[d];
    s = acc * 0.08838834764831845f;  // GH^-0.5
  }
  float m = s;
#pragma unroll
  for (int off = 32; off > 0; off >>= 1) m = fmaxf(m, __shfl_xor(m, off, 64));
  float e = (kb < 32 && kb <= qb) ? __expf(s - m) : 0.f;
  float sum = e;
#pragma unroll
  for (int off = 32; off > 0; off >>= 1) sum += __shfl_xor(sum, off, 64);
  if (kb < 32) {
    float gate = e / sum;
    bool keep = (kb <= qb) && (gate >= THRG || kb == qb);
    mask[((long)h * 32 + qb) * 32 + kb] = keep ? 1 : 0;
  }
}

// ---------------- RoPE + cast q,k -> head-major bf16 ----------------
__global__ __launch_bounds__(256) void k_rope(const float* __restrict__ qkv,
                                              const float* __restrict__ cosb,
                                              const float* __restrict__ sinb,
                                              short* __restrict__ q_bf,
                                              short* __restrict__ k_bf) {
  long id = (long)blockIdx.x * 256 + threadIdx.x;  // S * 20 * 64
  int d = (int)(id & 63);
  long rest = id >> 6;
  int head = (int)(rest % 20);
  int s = (int)(rest / 20);
  const float c = cosb[(long)s * HDIM + d];
  const float sn = sinb[(long)s * HDIM + d];
  if (head < HQ) {
    const float* src = qkv + (long)s * NQKV + head * HDIM;
    float x1 = src[d], x2 = src[d + 64];
    short* dst = q_bf + ((long)head * S_LEN + s) * HDIM;
    dst[d] = f2bf(x1 * c - x2 * sn);
    dst[d + 64] = f2bf(x2 * c + x1 * sn);
  } else {
    int hk = head - HQ;
    const float* src = qkv + (long)s * NQKV + 2048 + hk * HDIM;
    float x1 = src[d], x2 = src[d + 64];
    short* dst = k_bf + ((long)hk * S_LEN + s) * HDIM;
    dst[d] = f2bf(x1 * c - x2 * sn);
    dst[d + 64] = f2bf(x2 * c + x1 * sn);
  }
}

// ---------------- v transpose-cast: v_t[hk][d][s] ----------------
__global__ __launch_bounds__(256) void k_vcast(const float* __restrict__ qkv,
                                               short* __restrict__ v_t) {
  long id = (long)blockIdx.x * 256 + threadIdx.x;  // HKV*HDIM*S
  int s = (int)(id & (S_LEN - 1));
  long rest = id >> 11;
  int d = (int)(rest & 127);
  int hk = (int)(rest >> 7);
  v_t[id] = f2bf(qkv[(long)s * NQKV + 2560 + hk * HDIM + d]);
}

// ---------------- flash attention: LDS staging + S^T register softmax ----------------
// K/V staged block-wide via global_load_lds (no VGPR cost, 4x traffic reduction
// vs per-wave global fragments). LDS layout = m97-style panels of 64B rows:
//   Ks: 4 panels (kd)  of [64 rows x 32 shorts]   (16 KB)
//   Vs: 2 panels (ksb) of [128 rows x 32 shorts]  (16 KB)
// Panel gather done by permuting each lane's GLOBAL source address (LDS dest
// is fixed base+lane*16). S^T scheme: mfma(K-frag, Q-frag) -> lane owns one
// q-row; softmax = per-lane reduction + 2 cross-quad shuffles. P via per-wave
// LDS buffer with padded stride 72 shorts (no swizzle, ~2-way reads).
__global__ __launch_bounds__(256) void k_attn(const short* __restrict__ q_bf,
                                              const short* __restrict__ k_bf,
                                              const short* __restrict__ v_t,
                                              const unsigned char* __restrict__ mask,
                                              short* __restrict__ o_bf) {
  const int qb = blockIdx.x, h = blockIdx.y;
  const int tid = threadIdx.x, wave = tid >> 6, lane = tid & 63;
  const int quad = lane >> 4, l15 = lane & 15;
  __shared__ short Ks[4 * 64 * 32];   // panel kd: [row r][32]
  __shared__ short Vs[2 * 128 * 32];  // panel ksb: [d][32]
  __shared__ short Ps[4][16 * 72];    // per-wave P, padded stride 72 shorts
  short* Pw = Ps[wave];
  const int hk = h >> 2;
  const unsigned char* mptr = mask + ((long)h * 32 + qb) * 32;
  const float SCL = 0.08838834764831845f * 1.4426950408889634f;  // D^-.5 * log2e
  const int qrow_g = qb * 64 + wave * 16 + l15;  // this lane's q-row

  // Q B-frags (n = q-row indexed by l15), resident all kernel
  bf16x8 bq[4];
  {
    const short* qrp = q_bf + ((long)h * S_LEN + qrow_g) * HDIM + quad * 8;
#pragma unroll
    for (int kd = 0; kd < 4; kd++) bq[kd] = *(const bf16x8*)(qrp + kd * 32);
  }

  const short* kh = k_bf + (long)hk * S_LEN * HDIM;
  const short* vh = v_t + (long)hk * HDIM * S_LEN;

  // staging addresses: wave w loads K panel w (4 instrs x 16 rows),
  // V panel (w>>1) rows (w&1)*64.. (4 instrs x 16 rows). lane: i2=row, i3=chunk.
  const int i2 = lane >> 2, i3 = lane & 3;
  int koff[4], voff[4];
  const int vp = wave >> 1, vhh = wave & 1;
#pragma unroll
  for (int inst = 0; inst < 4; inst++) {
    koff[inst] = (inst * 16 + i2) * HDIM + wave * 32 + i3 * 8;
    voff[inst] = (vhh * 64 + inst * 16 + i2) * S_LEN + vp * 32 + i3 * 8;
  }

  f32x4 accO[8] = {};
  float mrow = -3.0e38f, lrow = 0.f;

  for (int kb = 0; kb <= qb; kb++) {
    if (!mptr[kb]) continue;  // block-uniform
    __syncthreads();  // prior iter's LDS reads done before overwrite
    {
      const int kg = kb * 64 * HDIM;
      const int vg = kb * 64;
#pragma unroll
      for (int inst = 0; inst < 4; inst++) {
        gload16(kh + kg + koff[inst], &Ks[wave * 2048 + inst * 512]);
        gload16(vh + vg + voff[inst], &Vs[vp * 4096 + (vhh * 64 + inst * 16) * 32]);
      }
    }
    __syncthreads();  // all staging landed (compiler drains vmcnt)

    // ---- S^T: 4 subtiles; lane ends with 16 scores for its q-row ----
    f32x4 sv[4];
#pragma unroll
    for (int nt = 0; nt < 4; nt++) {
      f32x4 t = {};
#pragma unroll
      for (int kd = 0; kd < 4; kd++) {
        bf16x8 ka = *(const bf16x8*)&Ks[kd * 2048 + (nt * 16 + l15) * 32 + quad * 8];
        t = __builtin_amdgcn_mfma_f32_16x16x32_bf16(ka, bq[kd], t, 0, 0, 0);
      }
      sv[nt] = t;
    }
    // ---- scale + mask + row max ----
    float lmx = -__builtin_inff();
    if (kb < qb) {
#pragma unroll
      for (int nt = 0; nt < 4; nt++)
#pragma unroll
        for (int r = 0; r < 4; r++) {
          sv[nt][r] *= SCL;
          lmx = fmaxf(lmx, sv[nt][r]);
        }
    } else {  // diagonal block
#pragma unroll
      for (int nt = 0; nt < 4; nt++)
#pragma unroll
        for (int r = 0; r < 4; r++) {
          const int kcol = kb * 64 + nt * 16 + quad * 4 + r;
          sv[nt][r] = (kcol <= qrow_g) ? sv[nt][r] * SCL : -__builtin_inff();
          lmx = fmaxf(lmx, sv[nt][r]);
        }
    }
    lmx = fmaxf(lmx, __shfl_xor(lmx, 16, 64));
    lmx = fmaxf(lmx, __shfl_xor(lmx, 32, 64));
    const float mnew = fmaxf(mrow, lmx);
    const float alpha = __builtin_amdgcn_exp2f(mrow - mnew);
    mrow = mnew;
    // ---- exp2 + sum + packed P write (padded stride, b64) ----
    float psum = 0.f;
#pragma unroll
    for (int nt = 0; nt < 4; nt++) {
#pragma unroll
      for (int r = 0; r < 4; r++) {
        float p = __builtin_amdgcn_exp2f(sv[nt][r] - mnew);
        sv[nt][r] = p;
        psum += p;
      }
      uint2 u;
      u.x = pack_bf2(sv[nt][1], sv[nt][0]);
      u.y = pack_bf2(sv[nt][3], sv[nt][2]);
      *(uint2*)&Pw[l15 * 72 + nt * 16 + quad * 4] = u;
    }
    psum += __shfl_xor(psum, 16, 64);
    psum += __shfl_xor(psum, 32, 64);
    lrow = lrow * alpha + psum;
    // ---- rescale accO (alpha broadcast: lane j<16 holds row j's alpha) ----
    float al[4];
#pragma unroll
    for (int r = 0; r < 4; r++) al[r] = __shfl(alpha, quad * 4 + r, 64);
#pragma unroll
    for (int dt = 0; dt < 8; dt++)
#pragma unroll
      for (int r = 0; r < 4; r++) accO[dt][r] *= al[r];
    // drain this wave's P writes before fragment reads (per-wave buffer)
    asm volatile("s_waitcnt lgkmcnt(0)" ::: "memory");
    // ---- PV: P(16x64) @ V^T panels ----
    bf16x8 pf[2];
#pragma unroll
    for (int ksb = 0; ksb < 2; ksb++)
      pf[ksb] = *(const bf16x8*)&Pw[l15 * 72 + ksb * 32 + quad * 8];
#pragma unroll
    for (int dt = 0; dt < 8; dt++) {
#pragma unroll
      for (int ksb = 0; ksb < 2; ksb++) {
        bf16x8 vf = *(const bf16x8*)&Vs[ksb * 4096 + (dt * 16 + l15) * 32 + quad * 8];
        accO[dt] = __builtin_amdgcn_mfma_f32_16x16x32_bf16(pf[ksb], vf, accO[dt], 0, 0, 0);
      }
    }
  }
  // ---- epilogue: normalize by l (broadcast like alpha) and store ----
  const float linv = 1.f / lrow;
  float li[4];
#pragma unroll
  for (int r = 0; r < 4; r++) li[r] = __shfl(linv, quad * 4 + r, 64);
#pragma unroll
  for (int r = 0; r < 4; r++) {
    const long srow = (long)qb * 64 + wave * 16 + quad * 4 + r;
#pragma unroll
    for (int dt = 0; dt < 8; dt++)
      o_bf[srow * HIDN + h * HDIM + dt * 16 + l15] = f2bf(accO[dt][r] * li[r]);
  }
}

// ---------------- workspace layout ----------------
static constexpr size_t SZ_WQKVT = (size_t)NQKV * HIDN * 2;
static constexpr size_t SZ_WOT = (size_t)HIDN * HIDN * 2;
static constexpr size_t SZ_WBIG = (size_t)INTER * HIDN * 2;
static constexpr size_t OFF_WQKVT = 0;
static constexpr size_t OFF_WOT = OFF_WQKVT + SZ_WQKVT;
static constexpr size_t OFF_WGATET = OFF_WOT + SZ_WOT;
static constexpr size_t OFF_WUPT = OFF_WGATET + SZ_WBIG;
static constexpr size_t OFF_WDOWNT = OFF_WUPT + SZ_WBIG;
static constexpr size_t OFF_BIAS = OFF_WDOWNT + SZ_WBIG;
static constexpr size_t OFF_MASK = OFF_BIAS + 3072 * 4 + 4096;
static constexpr size_t OFF_QM = OFF_MASK + 16 * 32 * 32 + 4096;
static constexpr size_t OFF_KM = OFF_QM + (size_t)32 * 16 * 128 * 4;
static constexpr size_t OFF_QG = OFF_KM + (size_t)32 * 4 * 128 * 4;
static constexpr size_t OFF_KG = OFF_QG + (size_t)32 * 16 * 128 * 4;
static constexpr size_t OFF_H2 = OFF_KG + (size_t)32 * 4 * 128 * 4;
static constexpr size_t OFF_H3 = OFF_H2 + (size_t)S_LEN * HIDN * 4;
static constexpr size_t OFF_REGA = OFF_H3 + (size_t)S_LEN * HIDN * 2;
//   REGA phase1: h_bf | q_bf | k_bf | v_t | o_bf ; phase2: act_bf (o_bf dead)
static constexpr size_t RA_HBF = 0;
static constexpr size_t RA_QBF = RA_HBF + (size_t)S_LEN * HIDN * 2;
static constexpr size_t RA_KBF = RA_QBF + (size_t)HQ * S_LEN * HDIM * 2;
static constexpr size_t RA_VT = RA_KBF + (size_t)HKV * S_LEN * HDIM * 2;
static constexpr size_t RA_OBF = RA_VT + (size_t)HKV * HDIM * S_LEN * 2;
static constexpr size_t SZ_REGA = RA_OBF + (size_t)S_LEN * HIDN * 2;
static constexpr size_t OFF_REGB = OFF_REGA + SZ_REGA;
//   REGB phase1: qkv_f32 (S x 3072 f32) ; phase2: g_bf (S x INTER bf16)
static constexpr size_t SZ_REGB = (size_t)S_LEN * NQKV * 4;
static constexpr size_t TOTAL_WS = OFF_REGB + SZ_REGB;

extern "C" void kernel_launch(void* const* d_in, const int* in_sizes, int n_in,
                              void* d_out, int out_size, void* d_ws, size_t ws_size,
                              hipStream_t stream) {
  const float* hidden = (const float*)d_in[0];
  const float* cosb = (const float*)d_in[1];
  const float* sinb = (const float*)d_in[2];
  const float* ln1 = (const float*)d_in[3];
  const float* ln2 = (const float*)d_in[4];
  const float* Wq = (const float*)d_in[5];
  const float* bq = (const float*)d_in[6];
  const float* Wk = (const float*)d_in[7];
  const float* bk = (const float*)d_in[8];
  const float* Wv = (const float*)d_in[9];
  const float* bv = (const float*)d_in[10];
  const float* Wo = (const float*)d_in[11];
  const float* gWq = (const float*)d_in[12];
  const float* gWk = (const float*)d_in[13];
  const float* Wgate = (const float*)d_in[14];
  const float* Wup = (const float*)d_in[15];
  const float* Wdown = (const float*)d_in[16];

  if (ws_size < TOTAL_WS) return;  // workspace too small; fail visibly

  char* ws = (char*)d_ws;
  short* WqkvT = (short*)(ws + OFF_WQKVT);
  short* WoT = (short*)(ws + OFF_WOT);
  short* WgateT = (short*)(ws + OFF_WGATET);
  short* WupT = (short*)(ws + OFF_WUPT);
  short* WdownT = (short*)(ws + OFF_WDOWNT);
  float* biasqkv = (float*)(ws + OFF_BIAS);
  unsigned char* maskb = (unsigned char*)(ws + OFF_MASK);
  float* qm = (float*)(ws + OFF_QM);
  float* km = (float*)(ws + OFF_KM);
  float* qg = (float*)(ws + OFF_QG);
  float* kg = (float*)(ws + OFF_KG);
  float* h2 = (float*)(ws + OFF_H2);
  short* h3_bf = (short*)(ws + OFF_H3);
  short* h_bf = (short*)(ws + OFF_REGA + RA_HBF);
  short* q_bf = (short*)(ws + OFF_REGA + RA_QBF);
  short* k_bf = (short*)(ws + OFF_REGA + RA_KBF);
  short* v_t = (short*)(ws + OFF_REGA + RA_VT);
  short* o_bf = (short*)(ws + OFF_REGA + RA_OBF);
  short* act_bf = (short*)(ws + OFF_REGA);  // overlays h_bf..v_t, all dead by then
  float* qkv_f = (float*)(ws + OFF_REGB);
  short* g_bf = (short*)(ws + OFF_REGB);  // overlays qkv_f, dead by then
  float* outp = (float*)d_out;

  dim3 tb(32, 8);
  // weight transposes (fp32 -> bf16, N x K)
  k_transpose_cast<<<dim3(64, 64), tb, 0, stream>>>(Wq, WqkvT, HIDN, 2048);
  k_transpose_cast<<<dim3(16, 64), tb, 0, stream>>>(Wk, WqkvT + (size_t)2048 * HIDN, HIDN, 512);
  k_transpose_cast<<<dim3(16, 64), tb, 0, stream>>>(Wv, WqkvT + (size_t)2560 * HIDN, HIDN, 512);
  k_transpose_cast<<<dim3(64, 64), tb, 0, stream>>>(Wo, WoT, HIDN, HIDN);
  k_transpose_cast<<<dim3(176, 64), tb, 0, stream>>>(Wgate, WgateT, HIDN, INTER);
  k_transpose_cast<<<dim3(176, 64), tb, 0, stream>>>(Wup, WupT, HIDN, INTER);
  k_transpose_cast<<<dim3(64, 176), tb, 0, stream>>>(Wdown, WdownT, INTER, HIDN);
  k_bias_concat<<<12, 256, 0, stream>>>(bq, bk, bv, biasqkv);

  // h = RMS(hidden, ln1) -> bf16
  k_rms<<<S_LEN, 256, 0, stream>>>(hidden, ln1, h_bf);
  // qkv = h @ [Wq|Wk|Wv] + bias  (fp32)
  k_gemm<0, 64><<<dim3(NQKV / 64, S_LEN / 128), 256, 0, stream>>>(
      h_bf, WqkvT, qkv_f, nullptr, biasqkv, nullptr, nullptr, S_LEN, NQKV, HIDN);
  // gate path (pre-RoPE q,k)
  k_blockmean<<<320, 256, 0, stream>>>(qkv_f, qm, km);
  k_gateproj<<<640, 128, 0, stream>>>(qm, km, gWq, gWk, qg, kg);
  k_gatemask<<<dim3(32, 16), 64, 0, stream>>>(qg, kg, maskb);
  // RoPE + layout change
  k_rope<<<10240, 256, 0, stream>>>(qkv_f, cosb, sinb, q_bf, k_bf);
  k_vcast<<<4096, 256, 0, stream>>>(qkv_f, v_t);
  // attention
  k_attn<<<dim3(32, 16), 256, 0, stream>>>(q_bf, k_bf, v_t, maskb, o_bf);
  // h2 = o @ Wo + hidden (fp32)
  k_gemm<0, 64><<<dim3(32, 16), 256, 0, stream>>>(
      o_bf, WoT, h2, nullptr, nullptr, hidden, nullptr, S_LEN, HIDN, HIDN);
  // h3 = RMS(h2, ln2) -> bf16
  k_rms<<<S_LEN, 256, 0, stream>>>(h2, ln2, h3_bf);
  // g = h3 @ Wgate (bf16)
  k_gemm<1, 128><<<dim3(INTER / 128, 16), 256, 0, stream>>>(
      h3_bf, WgateT, nullptr, g_bf, nullptr, nullptr, nullptr, S_LEN, INTER, HIDN);
  // act = silu(g) * (h3 @ Wup) (bf16)
  k_gemm<2, 128><<<dim3(INTER / 128, 16), 256, 0, stream>>>(
      h3_bf, WupT, nullptr, act_bf, nullptr, nullptr, g_bf, S_LEN, INTER, HIDN);
  // out = act @ Wdown + h2 (fp32)
  k_gemm<0, 64><<<dim3(32, 16), 256, 0, stream>>>(
      act_bf, WdownT, outp, nullptr, nullptr, h2, nullptr, S_LEN, HIDN, INTER);
  (void)in_sizes; (void)n_in; (void)out_size;
}

// Round 5
// 675.524 us; speedup vs baseline: 1.4233x; 1.1054x over previous
//
#include <hip/hip_runtime.h>
#include <stdint.h>
#include <stddef.h>

// ---------------- problem constants ----------------
#define S_LEN 2048
#define HIDN  2048
#define HQ    16
#define HKV   4
#define HDIM  128
#define NQKV  3072      // HQ*D + 2*HKV*D
#define QBLK  32        // S/64
#define GHW   128
#define INTER 5632
#define NEGF  (-1e30f)
#define THRG  0.004f

typedef short bf16x8 __attribute__((ext_vector_type(8)));
typedef float f32x4  __attribute__((ext_vector_type(4)));

__device__ __forceinline__ short f2bf(float f) {
  union { float f; unsigned u; } v; v.f = f;
  unsigned r = (v.u + 0x7FFFu + ((v.u >> 16) & 1u)) >> 16;
  return (short)r;
}
__device__ __forceinline__ float bf2f(short s) {
  union { float f; unsigned u; } v; v.u = ((unsigned)(unsigned short)s) << 16;
  return v.f;
}
__device__ __forceinline__ void gload16(const void* g, void* l) {
  __builtin_amdgcn_global_load_lds(
      (const __attribute__((address_space(1))) void*)g,
      (__attribute__((address_space(3))) void*)l, 16, 0, 0);
}
// pack two f32 -> [bf16(hi)<<16 | bf16(lo)] via byte-select (truncation)
__device__ __forceinline__ unsigned pack_bf2(float hi, float lo) {
  return __builtin_amdgcn_perm(__float_as_uint(hi), __float_as_uint(lo), 0x07060302u);
}

// ---------------- transpose + cast fp32 (R x C) -> bf16 (C x R) ----------------
__global__ __launch_bounds__(256) void k_transpose_cast(
    const float* __restrict__ src, short* __restrict__ dst, int R, int C) {
  __shared__ float t[32][33];
  const int tx = threadIdx.x, ty = threadIdx.y;
  const int x = blockIdx.x * 32 + tx;
  const int y0 = blockIdx.y * 32;
#pragma unroll
  for (int i = 0; i < 4; i++) {
    int yy = ty + i * 8;
    t[yy][tx] = src[(long)(y0 + yy) * C + x];
  }
  __syncthreads();
  const int xo = blockIdx.y * 32 + tx;
  const int yo0 = blockIdx.x * 32;
#pragma unroll
  for (int i = 0; i < 4; i++) {
    int yy = ty + i * 8;
    dst[(long)(yo0 + yy) * R + xo] = f2bf(t[tx][yy]);
  }
}

// ---------------- concat qkv bias ----------------
__global__ void k_bias_concat(const float* __restrict__ bq, const float* __restrict__ bk,
                              const float* __restrict__ bv, float* __restrict__ out) {
  int i = blockIdx.x * 256 + threadIdx.x;
  if (i < 2048) out[i] = bq[i];
  else if (i < 2560) out[i] = bk[i - 2048];
  else out[i] = bv[i - 2560];
}

// ---------------- RMSNorm fp32 -> bf16 ----------------
__global__ __launch_bounds__(256) void k_rms(const float* __restrict__ x,
                                             const float* __restrict__ w,
                                             short* __restrict__ out) {
  const int row = blockIdx.x;
  const float* xr = x + (long)row * HIDN;
  float v[8];
  float ss = 0.f;
#pragma unroll
  for (int i = 0; i < 8; i++) {
    v[i] = xr[threadIdx.x + i * 256];
    ss += v[i] * v[i];
  }
#pragma unroll
  for (int off = 32; off > 0; off >>= 1) ss += __shfl_down(ss, off, 64);
  __shared__ float red[4];
  const int wave = threadIdx.x >> 6, lane = threadIdx.x & 63;
  if (lane == 0) red[wave] = ss;
  __syncthreads();
  float tot = red[0] + red[1] + red[2] + red[3];
  float rs = rsqrtf(tot / (float)HIDN + 1e-6f);
#pragma unroll
  for (int i = 0; i < 8; i++) {
    int c = threadIdx.x + i * 256;
    out[(long)row * HIDN + c] = f2bf(v[i] * rs * w[c]);
  }
}

// ---------------- GEMM: C[M,N] = A[M,K](bf16) * Bt[N,K](bf16)^T  ----------------
// MODE 0: Cf = acc + bias? + add?   (fp32 out)
// MODE 1: Cb = bf16(acc)
// MODE 2: Cb = bf16(silu(gaux) * acc)
// BN in {64,128}. BK=64: tiles stored as two k-half panels [2][rows][32]
// (64B rows -> 2-way/free LDS reads), halving barrier count vs BK=32.
template <int MODE, int BN>
__global__ __launch_bounds__(256) void k_gemm(
    const short* __restrict__ A, const short* __restrict__ Bt,
    float* __restrict__ Cf, short* __restrict__ Cb,
    const float* __restrict__ bias, const float* __restrict__ add,
    const short* __restrict__ gaux, int M, int N, int K) {
  constexpr int NT = BN / 32;   // n-tiles per wave
  constexpr int BIW = BN / 32;  // per-wave B staging instrs
  constexpr int BPP = BN / 16;  // B staging instrs per k-half panel
  __shared__ short As[2][128][32];
  __shared__ short Bs[2][BN][32];
  const int tid = threadIdx.x;
  const int wave = tid >> 6, lane = tid & 63, quad = lane >> 4, l15 = lane & 15;
  const long m0 = (long)blockIdx.y * 128, n0 = (long)blockIdx.x * BN;
  const int wr = (wave >> 1) * 64, wc = (wave & 1) * (BN / 2);
  const int i2 = lane >> 2, i3 = lane & 3;
  f32x4 acc[4][NT] = {};
  // A staging: 16 instrs (4/wave). instr g: k-half h=g>>3, rows (g&7)*16..+15
  const short* Ainst[4];
  short* Alds[4];
#pragma unroll
  for (int j = 0; j < 4; j++) {
    const int g = wave * 4 + j, h = g >> 3, rb = (g & 7) * 16;
    Ainst[j] = A + (m0 + rb + i2) * K + h * 32 + i3 * 8;
    Alds[j] = &As[h][rb][0];
  }
  // B staging: BN/8 instrs (BIW/wave)
  const short* Binst[BIW];
  short* Blds[BIW];
#pragma unroll
  for (int j = 0; j < BIW; j++) {
    const int g = wave * BIW + j, h = g / BPP, rb = (g % BPP) * 16;
    Binst[j] = Bt + (n0 + rb + i2) * K + h * 32 + i3 * 8;
    Blds[j] = &Bs[h][rb][0];
  }
  for (int k0 = 0; k0 < K; k0 += 64) {
    __syncthreads();
#pragma unroll
    for (int j = 0; j < 4; j++) gload16(Ainst[j] + k0, Alds[j]);
#pragma unroll
    for (int j = 0; j < BIW; j++) gload16(Binst[j] + k0, Blds[j]);
    __syncthreads();
#pragma unroll
    for (int s = 0; s < 2; s++) {
      bf16x8 af[4], bb[NT];
#pragma unroll
      for (int mi = 0; mi < 4; mi++)
        af[mi] = *(const bf16x8*)&As[s][wr + mi * 16 + l15][quad * 8];
#pragma unroll
      for (int ni = 0; ni < NT; ni++)
        bb[ni] = *(const bf16x8*)&Bs[s][wc + ni * 16 + l15][quad * 8];
#pragma unroll
      for (int mi = 0; mi < 4; mi++)
#pragma unroll
        for (int ni = 0; ni < NT; ni++)
          acc[mi][ni] = __builtin_amdgcn_mfma_f32_16x16x32_bf16(af[mi], bb[ni], acc[mi][ni], 0, 0, 0);
    }
  }
  const bool hb = (MODE == 0) && (bias != nullptr);
  const bool ha = (MODE == 0) && (add != nullptr);
#pragma unroll
  for (int mi = 0; mi < 4; mi++) {
#pragma unroll
    for (int ni = 0; ni < NT; ni++) {
      long mbase = m0 + wr + mi * 16 + quad * 4;
      long n = n0 + wc + ni * 16 + l15;
#pragma unroll
      for (int r = 0; r < 4; r++) {
        float v = acc[mi][ni][r];
        long idx = (mbase + r) * N + n;
        if (MODE == 0) {
          if (hb) v += bias[n];
          if (ha) v += add[idx];
          Cf[idx] = v;
        } else if (MODE == 1) {
          Cb[idx] = f2bf(v);
        } else {
          float g = bf2f(gaux[idx]);
          float sg = g / (1.f + __expf(-g));
          Cb[idx] = f2bf(sg * v);
        }
      }
    }
  }
}

// ---------------- block means of q and k (pre-RoPE) ----------------
__global__ __launch_bounds__(256) void k_blockmean(const float* __restrict__ qkv,
                                                   float* __restrict__ qm,
                                                   float* __restrict__ km) {
  int id = blockIdx.x * 256 + threadIdx.x;  // 32 * 2560
  int qb = id / 2560, c = id % 2560;        // cols 0..2559 = q(2048) + k(512)
  const float* base = qkv + (long)qb * 64 * NQKV + c;
  float acc = 0.f;
  for (int s = 0; s < 64; s++) acc += base[(long)s * NQKV];
  acc *= (1.f / 64.f);
  if (c < 2048) qm[(long)qb * 2048 + c] = acc;
  else km[(long)qb * 512 + (c - 2048)] = acc;
}

// ---------------- gate projections qg = qm@gWq, kg = km@gWk ----------------
__global__ __launch_bounds__(128) void k_gateproj(const float* __restrict__ qm,
                                                  const float* __restrict__ km,
                                                  const float* __restrict__ gWq,
                                                  const float* __restrict__ gWk,
                                                  float* __restrict__ qg,
                                                  float* __restrict__ kg) {
  __shared__ float xm[128];
  const int b = blockIdx.x;
  const float* src; const float* W; float* dst;
  if (b < 512) { src = qm + (long)b * 128; W = gWq; dst = qg + (long)b * 128; }
  else { int r = b - 512; src = km + (long)r * 128; W = gWk; dst = kg + (long)r * 128; }
  xm[threadIdx.x] = src[threadIdx.x];
  __syncthreads();
  float acc = 0.f;
  for (int d = 0; d < 128; d++) acc += xm[d] * W[d * GHW + threadIdx.x];
  dst[threadIdx.x] = acc;
}

// ---------------- gate softmax + keep mask ----------------
__global__ __launch_bounds__(64) void k_gatemask(const float* __restrict__ qg,
                                                 const float* __restrict__ kg,
                                                 unsigned char* __restrict__ mask) {
  const int qb = blockIdx.x, h = blockIdx.y;
  __shared__ float qv[128];
  const int t = threadIdx.x;
  qv[t] = qg[((long)qb * 16 + h) * 128 + t];
  qv[t + 64] = qg[((long)qb * 16 + h) * 128 + t + 64];
  __syncthreads();
  const int kb = t;
  float s = NEGF;
  if (kb < 32 && kb <= qb) {
    const float* kr = kg + ((long)kb * 4 + (h >> 2)) * 128;
    float acc = 0.f;
    for (int d = 0; d < 128; d++) acc += qv[d] * kr[d];
    s = acc * 0.08838834764831845f;  // GH^-0.5
  }
  float m = s;
#pragma unroll
  for (int off = 32; off > 0; off >>= 1) m = fmaxf(m, __shfl_xor(m, off, 64));
  float e = (kb < 32 && kb <= qb) ? __expf(s - m) : 0.f;
  float sum = e;
#pragma unroll
  for (int off = 32; off > 0; off >>= 1) sum += __shfl_xor(sum, off, 64);
  if (kb < 32) {
    float gate = e / sum;
    bool keep = (kb <= qb) && (gate >= THRG || kb == qb);
    mask[((long)h * 32 + qb) * 32 + kb] = keep ? 1 : 0;
  }
}

// ---------------- RoPE + cast q,k -> head-major bf16 ----------------
__global__ __launch_bounds__(256) void k_rope(const float* __restrict__ qkv,
                                              const float* __restrict__ cosb,
                                              const float* __restrict__ sinb,
                                              short* __restrict__ q_bf,
                                              short* __restrict__ k_bf) {
  long id = (long)blockIdx.x * 256 + threadIdx.x;  // S * 20 * 64
  int d = (int)(id & 63);
  long rest = id >> 6;
  int head = (int)(rest % 20);
  int s = (int)(rest / 20);
  const float c = cosb[(long)s * HDIM + d];
  const float sn = sinb[(long)s * HDIM + d];
  if (head < HQ) {
    const float* src = qkv + (long)s * NQKV + head * HDIM;
    float x1 = src[d], x2 = src[d + 64];
    short* dst = q_bf + ((long)head * S_LEN + s) * HDIM;
    dst[d] = f2bf(x1 * c - x2 * sn);
    dst[d + 64] = f2bf(x2 * c + x1 * sn);
  } else {
    int hk = head - HQ;
    const float* src = qkv + (long)s * NQKV + 2048 + hk * HDIM;
    float x1 = src[d], x2 = src[d + 64];
    short* dst = k_bf + ((long)hk * S_LEN + s) * HDIM;
    dst[d] = f2bf(x1 * c - x2 * sn);
    dst[d + 64] = f2bf(x2 * c + x1 * sn);
  }
}

// ---------------- v transpose-cast: v_t[hk][d][s] ----------------
__global__ __launch_bounds__(256) void k_vcast(const float* __restrict__ qkv,
                                               short* __restrict__ v_t) {
  long id = (long)blockIdx.x * 256 + threadIdx.x;  // HKV*HDIM*S
  int s = (int)(id & (S_LEN - 1));
  long rest = id >> 11;
  int d = (int)(rest & 127);
  int hk = (int)(rest >> 7);
  v_t[id] = f2bf(qkv[(long)s * NQKV + 2560 + hk * HDIM + d]);
}

// ---------------- flash attention: LDS staging + S^T register softmax ----------------
__global__ __launch_bounds__(256) void k_attn(const short* __restrict__ q_bf,
                                              const short* __restrict__ k_bf,
                                              const short* __restrict__ v_t,
                                              const unsigned char* __restrict__ mask,
                                              short* __restrict__ o_bf) {
  const int qb = blockIdx.x, h = blockIdx.y;
  const int tid = threadIdx.x, wave = tid >> 6, lane = tid & 63;
  const int quad = lane >> 4, l15 = lane & 15;
  __shared__ short Ks[4 * 64 * 32];   // panel kd: [row r][32]
  __shared__ short Vs[2 * 128 * 32];  // panel ksb: [d][32]
  __shared__ short Ps[4][16 * 72];    // per-wave P, padded stride 72 shorts
  short* Pw = Ps[wave];
  const int hk = h >> 2;
  const unsigned char* mptr = mask + ((long)h * 32 + qb) * 32;
  const float SCL = 0.08838834764831845f * 1.4426950408889634f;  // D^-.5 * log2e
  const int qrow_g = qb * 64 + wave * 16 + l15;  // this lane's q-row

  // Q B-frags (n = q-row indexed by l15), resident all kernel
  bf16x8 bq[4];
  {
    const short* qrp = q_bf + ((long)h * S_LEN + qrow_g) * HDIM + quad * 8;
#pragma unroll
    for (int kd = 0; kd < 4; kd++) bq[kd] = *(const bf16x8*)(qrp + kd * 32);
  }

  const short* kh = k_bf + (long)hk * S_LEN * HDIM;
  const short* vh = v_t + (long)hk * HDIM * S_LEN;

  const int i2 = lane >> 2, i3 = lane & 3;
  int koff[4], voff[4];
  const int vp = wave >> 1, vhh = wave & 1;
#pragma unroll
  for (int inst = 0; inst < 4; inst++) {
    koff[inst] = (inst * 16 + i2) * HDIM + wave * 32 + i3 * 8;
    voff[inst] = (vhh * 64 + inst * 16 + i2) * S_LEN + vp * 32 + i3 * 8;
  }

  f32x4 accO[8] = {};
  float mrow = -3.0e38f, lrow = 0.f;

  for (int kb = 0; kb <= qb; kb++) {
    if (!mptr[kb]) continue;  // block-uniform
    __syncthreads();  // prior iter's LDS reads done before overwrite
    {
      const int kg = kb * 64 * HDIM;
      const int vg = kb * 64;
#pragma unroll
      for (int inst = 0; inst < 4; inst++) {
        gload16(kh + kg + koff[inst], &Ks[wave * 2048 + inst * 512]);
        gload16(vh + vg + voff[inst], &Vs[vp * 4096 + (vhh * 64 + inst * 16) * 32]);
      }
    }
    __syncthreads();  // all staging landed (compiler drains vmcnt)

    // ---- S^T: 4 subtiles; lane ends with 16 scores for its q-row ----
    f32x4 sv[4];
#pragma unroll
    for (int nt = 0; nt < 4; nt++) {
      f32x4 t = {};
#pragma unroll
      for (int kd = 0; kd < 4; kd++) {
        bf16x8 ka = *(const bf16x8*)&Ks[kd * 2048 + (nt * 16 + l15) * 32 + quad * 8];
        t = __builtin_amdgcn_mfma_f32_16x16x32_bf16(ka, bq[kd], t, 0, 0, 0);
      }
      sv[nt] = t;
    }
    // ---- scale + mask + row max ----
    float lmx = -__builtin_inff();
    if (kb < qb) {
#pragma unroll
      for (int nt = 0; nt < 4; nt++)
#pragma unroll
        for (int r = 0; r < 4; r++) {
          sv[nt][r] *= SCL;
          lmx = fmaxf(lmx, sv[nt][r]);
        }
    } else {  // diagonal block
#pragma unroll
      for (int nt = 0; nt < 4; nt++)
#pragma unroll
        for (int r = 0; r < 4; r++) {
          const int kcol = kb * 64 + nt * 16 + quad * 4 + r;
          sv[nt][r] = (kcol <= qrow_g) ? sv[nt][r] * SCL : -__builtin_inff();
          lmx = fmaxf(lmx, sv[nt][r]);
        }
    }
    lmx = fmaxf(lmx, __shfl_xor(lmx, 16, 64));
    lmx = fmaxf(lmx, __shfl_xor(lmx, 32, 64));
    const float mnew = fmaxf(mrow, lmx);
    const float alpha = __builtin_amdgcn_exp2f(mrow - mnew);
    mrow = mnew;
    // ---- exp2 + sum + packed P write (padded stride, b64) ----
    float psum = 0.f;
#pragma unroll
    for (int nt = 0; nt < 4; nt++) {
#pragma unroll
      for (int r = 0; r < 4; r++) {
        float p = __builtin_amdgcn_exp2f(sv[nt][r] - mnew);
        sv[nt][r] = p;
        psum += p;
      }
      uint2 u;
      u.x = pack_bf2(sv[nt][1], sv[nt][0]);
      u.y = pack_bf2(sv[nt][3], sv[nt][2]);
      *(uint2*)&Pw[l15 * 72 + nt * 16 + quad * 4] = u;
    }
    psum += __shfl_xor(psum, 16, 64);
    psum += __shfl_xor(psum, 32, 64);
    lrow = lrow * alpha + psum;
    // ---- rescale accO (alpha broadcast: lane j<16 holds row j's alpha) ----
    float al[4];
#pragma unroll
    for (int r = 0; r < 4; r++) al[r] = __shfl(alpha, quad * 4 + r, 64);
#pragma unroll
    for (int dt = 0; dt < 8; dt++)
#pragma unroll
      for (int r = 0; r < 4; r++) accO[dt][r] *= al[r];
    // drain this wave's P writes before fragment reads (per-wave buffer)
    asm volatile("s_waitcnt lgkmcnt(0)" ::: "memory");
    // ---- PV: P(16x64) @ V^T panels ----
    bf16x8 pf[2];
#pragma unroll
    for (int ksb = 0; ksb < 2; ksb++)
      pf[ksb] = *(const bf16x8*)&Pw[l15 * 72 + ksb * 32 + quad * 8];
#pragma unroll
    for (int dt = 0; dt < 8; dt++) {
#pragma unroll
      for (int ksb = 0; ksb < 2; ksb++) {
        bf16x8 vf = *(const bf16x8*)&Vs[ksb * 4096 + (dt * 16 + l15) * 32 + quad * 8];
        accO[dt] = __builtin_amdgcn_mfma_f32_16x16x32_bf16(pf[ksb], vf, accO[dt], 0, 0, 0);
      }
    }
  }
  // ---- epilogue: normalize by l (broadcast like alpha) and store ----
  const float linv = 1.f / lrow;
  float li[4];
#pragma unroll
  for (int r = 0; r < 4; r++) li[r] = __shfl(linv, quad * 4 + r, 64);
#pragma unroll
  for (int r = 0; r < 4; r++) {
    const long srow = (long)qb * 64 + wave * 16 + quad * 4 + r;
#pragma unroll
    for (int dt = 0; dt < 8; dt++)
      o_bf[srow * HIDN + h * HDIM + dt * 16 + l15] = f2bf(accO[dt][r] * li[r]);
  }
}

// ---------------- workspace layout ----------------
static constexpr size_t SZ_WQKVT = (size_t)NQKV * HIDN * 2;
static constexpr size_t SZ_WOT = (size_t)HIDN * HIDN * 2;
static constexpr size_t SZ_WBIG = (size_t)INTER * HIDN * 2;
static constexpr size_t OFF_WQKVT = 0;
static constexpr size_t OFF_WOT = OFF_WQKVT + SZ_WQKVT;
static constexpr size_t OFF_WGATET = OFF_WOT + SZ_WOT;
static constexpr size_t OFF_WUPT = OFF_WGATET + SZ_WBIG;
static constexpr size_t OFF_WDOWNT = OFF_WUPT + SZ_WBIG;
static constexpr size_t OFF_BIAS = OFF_WDOWNT + SZ_WBIG;
static constexpr size_t OFF_MASK = OFF_BIAS + 3072 * 4 + 4096;
static constexpr size_t OFF_QM = OFF_MASK + 16 * 32 * 32 + 4096;
static constexpr size_t OFF_KM = OFF_QM + (size_t)32 * 16 * 128 * 4;
static constexpr size_t OFF_QG = OFF_KM + (size_t)32 * 4 * 128 * 4;
static constexpr size_t OFF_KG = OFF_QG + (size_t)32 * 16 * 128 * 4;
static constexpr size_t OFF_H2 = OFF_KG + (size_t)32 * 4 * 128 * 4;
static constexpr size_t OFF_H3 = OFF_H2 + (size_t)S_LEN * HIDN * 4;
static constexpr size_t OFF_REGA = OFF_H3 + (size_t)S_LEN * HIDN * 2;
//   REGA phase1: h_bf | q_bf | k_bf | v_t | o_bf ; phase2: act_bf (o_bf dead)
static constexpr size_t RA_HBF = 0;
static constexpr size_t RA_QBF = RA_HBF + (size_t)S_LEN * HIDN * 2;
static constexpr size_t RA_KBF = RA_QBF + (size_t)HQ * S_LEN * HDIM * 2;
static constexpr size_t RA_VT = RA_KBF + (size_t)HKV * S_LEN * HDIM * 2;
static constexpr size_t RA_OBF = RA_VT + (size_t)HKV * HDIM * S_LEN * 2;
static constexpr size_t SZ_REGA = RA_OBF + (size_t)S_LEN * HIDN * 2;
static constexpr size_t OFF_REGB = OFF_REGA + SZ_REGA;
//   REGB phase1: qkv_f32 (S x 3072 f32) ; phase2: g_bf (S x INTER bf16)
static constexpr size_t SZ_REGB = (size_t)S_LEN * NQKV * 4;
static constexpr size_t TOTAL_WS = OFF_REGB + SZ_REGB;

extern "C" void kernel_launch(void* const* d_in, const int* in_sizes, int n_in,
                              void* d_out, int out_size, void* d_ws, size_t ws_size,
                              hipStream_t stream) {
  const float* hidden = (const float*)d_in[0];
  const float* cosb = (const float*)d_in[1];
  const float* sinb = (const float*)d_in[2];
  const float* ln1 = (const float*)d_in[3];
  const float* ln2 = (const float*)d_in[4];
  const float* Wq = (const float*)d_in[5];
  const float* bq = (const float*)d_in[6];
  const float* Wk = (const float*)d_in[7];
  const float* bk = (const float*)d_in[8];
  const float* Wv = (const float*)d_in[9];
  const float* bv = (const float*)d_in[10];
  const float* Wo = (const float*)d_in[11];
  const float* gWq = (const float*)d_in[12];
  const float* gWk = (const float*)d_in[13];
  const float* Wgate = (const float*)d_in[14];
  const float* Wup = (const float*)d_in[15];
  const float* Wdown = (const float*)d_in[16];

  if (ws_size < TOTAL_WS) return;  // workspace too small; fail visibly

  char* ws = (char*)d_ws;
  short* WqkvT = (short*)(ws + OFF_WQKVT);
  short* WoT = (short*)(ws + OFF_WOT);
  short* WgateT = (short*)(ws + OFF_WGATET);
  short* WupT = (short*)(ws + OFF_WUPT);
  short* WdownT = (short*)(ws + OFF_WDOWNT);
  float* biasqkv = (float*)(ws + OFF_BIAS);
  unsigned char* maskb = (unsigned char*)(ws + OFF_MASK);
  float* qm = (float*)(ws + OFF_QM);
  float* km = (float*)(ws + OFF_KM);
  float* qg = (float*)(ws + OFF_QG);
  float* kg = (float*)(ws + OFF_KG);
  float* h2 = (float*)(ws + OFF_H2);
  short* h3_bf = (short*)(ws + OFF_H3);
  short* h_bf = (short*)(ws + OFF_REGA + RA_HBF);
  short* q_bf = (short*)(ws + OFF_REGA + RA_QBF);
  short* k_bf = (short*)(ws + OFF_REGA + RA_KBF);
  short* v_t = (short*)(ws + OFF_REGA + RA_VT);
  short* o_bf = (short*)(ws + OFF_REGA + RA_OBF);
  short* act_bf = (short*)(ws + OFF_REGA);  // overlays h_bf..v_t, all dead by then
  float* qkv_f = (float*)(ws + OFF_REGB);
  short* g_bf = (short*)(ws + OFF_REGB);  // overlays qkv_f, dead by then
  float* outp = (float*)d_out;

  dim3 tb(32, 8);
  // weight transposes (fp32 -> bf16, N x K)
  k_transpose_cast<<<dim3(64, 64), tb, 0, stream>>>(Wq, WqkvT, HIDN, 2048);
  k_transpose_cast<<<dim3(16, 64), tb, 0, stream>>>(Wk, WqkvT + (size_t)2048 * HIDN, HIDN, 512);
  k_transpose_cast<<<dim3(16, 64), tb, 0, stream>>>(Wv, WqkvT + (size_t)2560 * HIDN, HIDN, 512);
  k_transpose_cast<<<dim3(64, 64), tb, 0, stream>>>(Wo, WoT, HIDN, HIDN);
  k_transpose_cast<<<dim3(176, 64), tb, 0, stream>>>(Wgate, WgateT, HIDN, INTER);
  k_transpose_cast<<<dim3(176, 64), tb, 0, stream>>>(Wup, WupT, HIDN, INTER);
  k_transpose_cast<<<dim3(64, 176), tb, 0, stream>>>(Wdown, WdownT, INTER, HIDN);
  k_bias_concat<<<12, 256, 0, stream>>>(bq, bk, bv, biasqkv);

  // h = RMS(hidden, ln1) -> bf16
  k_rms<<<S_LEN, 256, 0, stream>>>(hidden, ln1, h_bf);
  // qkv = h @ [Wq|Wk|Wv] + bias  (fp32)
  k_gemm<0, 64><<<dim3(NQKV / 64, S_LEN / 128), 256, 0, stream>>>(
      h_bf, WqkvT, qkv_f, nullptr, biasqkv, nullptr, nullptr, S_LEN, NQKV, HIDN);
  // gate path (pre-RoPE q,k)
  k_blockmean<<<320, 256, 0, stream>>>(qkv_f, qm, km);
  k_gateproj<<<640, 128, 0, stream>>>(qm, km, gWq, gWk, qg, kg);
  k_gatemask<<<dim3(32, 16), 64, 0, stream>>>(qg, kg, maskb);
  // RoPE + layout change
  k_rope<<<10240, 256, 0, stream>>>(qkv_f, cosb, sinb, q_bf, k_bf);
  k_vcast<<<4096, 256, 0, stream>>>(qkv_f, v_t);
  // attention
  k_attn<<<dim3(32, 16), 256, 0, stream>>>(q_bf, k_bf, v_t, maskb, o_bf);
  // h2 = o @ Wo + hidden (fp32)
  k_gemm<0, 64><<<dim3(32, 16), 256, 0, stream>>>(
      o_bf, WoT, h2, nullptr, nullptr, hidden, nullptr, S_LEN, HIDN, HIDN);
  // h3 = RMS(h2, ln2) -> bf16
  k_rms<<<S_LEN, 256, 0, stream>>>(h2, ln2, h3_bf);
  // g = h3 @ Wgate (bf16)
  k_gemm<1, 128><<<dim3(INTER / 128, 16), 256, 0, stream>>>(
      h3_bf, WgateT, nullptr, g_bf, nullptr, nullptr, nullptr, S_LEN, INTER, HIDN);
  // act = silu(g) * (h3 @ Wup) (bf16)
  k_gemm<2, 128><<<dim3(INTER / 128, 16), 256, 0, stream>>>(
      h3_bf, WupT, nullptr, act_bf, nullptr, nullptr, g_bf, S_LEN, INTER, HIDN);
  // out = act @ Wdown + h2 (fp32)
  k_gemm<0, 64><<<dim3(32, 16), 256, 0, stream>>>(
      act_bf, WdownT, outp, nullptr, nullptr, h2, nullptr, S_LEN, HIDN, INTER);
  (void)in_sizes; (void)n_in; (void)out_size;
}